// Round 19
// baseline (540.974 us; speedup 1.0000x reference)
//
#include <hip/hip_runtime.h>
#include <math.h>

#define BB 16
#define PP 512
#define DD 256
#define HH 8
#define NPAD 512
#define NVAL 449
#define MM (BB*PP)   // 8192
#define NROWS (BB*HH*NPAD)  // 65536

typedef unsigned short u16;
typedef unsigned u32;
typedef __bf16 v8bf __attribute__((ext_vector_type(8)));
typedef float v4f __attribute__((ext_vector_type(4)));
typedef unsigned short u16x8 __attribute__((ext_vector_type(8)));
typedef unsigned short u16x4 __attribute__((ext_vector_type(4)));

static __device__ __forceinline__ float b2f(u16 u) {
  unsigned v = ((unsigned)u) << 16;
  return __builtin_bit_cast(float, v);
}
static __device__ __forceinline__ u16 f2b(float f) {
  unsigned x = __builtin_bit_cast(unsigned, f);
  unsigned lsb = (x >> 16) & 1u;
  x += 0x7fffu + lsb;
  return (u16)(x >> 16);
}
static __device__ __forceinline__ v8bf ldg8(const u16* p) {
  u16x8 u = *(const u16x8*)p;
  return __builtin_bit_cast(v8bf, u);
}
static __device__ __forceinline__ void gload16(const u16* g, u16* l) {
  __builtin_amdgcn_global_load_lds(
      (__attribute__((address_space(1))) void*)(g),
      (__attribute__((address_space(3))) void*)(l), 16, 0, 0);
}

// ---------------- prep: gather x rows + geometry ----------------
__global__ void k_prep(const float* embeds, const float* xmin, const float* xmax,
                       const float* ymin, const float* ymax, const float* width,
                       const float* height, const float* empty_embed, const int* page_ids,
                       float* xf, u16* xb, float* gcx, float* gcy, float* gw, float* gh_) {
  int bx = blockIdx.x;            // 8192 = b*512 + r
  int b = bx >> 9, r = bx & 511;
  int t = threadIdx.x;            // 64
  int c0 = t * 4;
  const float* src = nullptr;
  if (r == 0) src = empty_embed;
  else if (r <= 448) {
    int gi = page_ids[b * PP + (r - 1)];
    src = embeds + (size_t)gi * DD;
  }
  float4 fv = make_float4(0.f, 0.f, 0.f, 0.f);
  if (src) fv = *(const float4*)(src + c0);
  size_t row = (size_t)b * NPAD + r;
  *(float4*)(xf + row * DD + c0) = fv;
  u16x4 bv; bv[0] = f2b(fv.x); bv[1] = f2b(fv.y); bv[2] = f2b(fv.z); bv[3] = f2b(fv.w);
  *(u16x4*)(xb + row * DD + c0) = bv;
  if (t == 0) {
    int p = r;
    int gi = page_ids[b * PP + p];
    float cx = 0.f, cy = 0.f, ww = 1.f, hh = 1.f;
    if (gi >= 0) {
      cx = 0.5f * (xmin[gi] + xmax[gi]);
      cy = 0.5f * (ymin[gi] + ymax[gi]);
      ww = fmaxf(width[gi], 1e-3f);
      hh = fmaxf(height[gi], 1e-3f);
    }
    gcx[b * PP + p] = cx; gcy[b * PP + p] = cy;
    gw[b * PP + p] = ww;  gh_[b * PP + p] = hh;
  }
}

// ---------------- rel indices (once): relp[b][i][j] = zx | zy<<8 ----------------
__global__ __launch_bounds__(64) void k_rel(const float* gcx, const float* gcy,
                                            const float* gw, const float* gh_, u16* relp) {
  int bx = blockIdx.x;            // 8192 = b*512 + i
  int b = bx >> 9, i = bx & 511;
  int t = threadIdx.x;
  float cxi = 0.f, cyi = 0.f, wi = 1.f, hi = 1.f;
  if (i > 0) {
    cxi = gcx[b * PP + i - 1]; cyi = gcy[b * PP + i - 1];
    wi = gw[b * PP + i - 1];   hi = gh_[b * PP + i - 1];
  }
  u16* dst = relp + ((size_t)b * NPAD + i) * NPAD;
#pragma unroll
  for (int jj = 0; jj < 8; jj++) {
    int j = jj * 64 + t;
    u16 pk = (u16)(32 | (32 << 8));
    if (j > 0) {
      float cxj = gcx[b * PP + j - 1], cyj = gcy[b * PP + j - 1];
      float dxf = rintf((cxj - cxi) / wi);
      float dyf = rintf((cyj - cyi) / hi);
      int zx = (int)(fminf(fmaxf(dxf, -32.f), 31.f)) + 32;
      int zy = (int)(fminf(fmaxf(dyf, -32.f), 31.f)) + 32;
      pk = (u16)(zx | (zy << 8));
    }
    dst[j] = pk;
  }
}

// ---------------- weight transposes (once) ----------------
__global__ __launch_bounds__(256) void k_wT(const float* cq, const float* ck, const float* cv,
                                            const float* ow, const float* f1, const float* f2,
                                            u16* wT) {
  __shared__ u16 lds[32][33];
  int bx = blockIdx.x;           // 2048
  int l = bx >> 9, r = bx & 511;
  const float* src; int N, k0, n0; u16* dst; int dstStride;
  if (r < 192) {
    int mat = r / 64, rr = r % 64;
    k0 = (rr >> 3) * 32; n0 = (rr & 7) * 32;
    src = (mat == 0 ? cq : mat == 1 ? ck : cv) + (size_t)l * 65536;
    N = 256; dst = wT + (size_t)l * 524288 + mat * 65536; dstStride = 256;
  } else if (r < 256) {
    int rr = r - 192;
    k0 = (rr >> 3) * 32; n0 = (rr & 7) * 32;
    src = ow + (size_t)l * 65536; N = 256;
    dst = wT + (size_t)l * 524288 + 196608; dstStride = 256;
  } else if (r < 384) {
    int rr = r - 256;
    k0 = (rr >> 4) * 32; n0 = (rr & 15) * 32;
    src = f1 + (size_t)l * 131072; N = 512;
    dst = wT + (size_t)l * 524288 + 262144; dstStride = 256;
  } else {
    int rr = r - 384;
    k0 = (rr >> 3) * 32; n0 = (rr & 7) * 32;
    src = f2 + (size_t)l * 131072; N = 256;
    dst = wT + (size_t)l * 524288 + 393216; dstStride = 512;
  }
  int tx = threadIdx.x & 31, ty = threadIdx.x >> 5;
#pragma unroll
  for (int yy = 0; yy < 4; yy++) {
    int y = ty + yy * 8;
    lds[y][tx] = f2b(src[(size_t)(k0 + y) * N + n0 + tx]);
  }
  __syncthreads();
#pragma unroll
  for (int yy = 0; yy < 4; yy++) {
    int y = ty + yy * 8;
    dst[(size_t)(n0 + y) * dstStride + k0 + tx] = lds[tx][y];
  }
}

// ---------------- position projections: [L][16 ch][64 z][16 d] bf16, ch=c*8+h ----------------
__global__ __launch_bounds__(256) void k_posproj(const float* pe, const float* pkw, const float* pkb,
                                                 const float* pqw, const float* pqb,
                                                 u16* pkfsw, u16* pqfsw) {
  int gid = blockIdx.x * 256 + threadIdx.x;   // 131072
  int d = gid & 15, z = (gid >> 4) & 63, ch = (gid >> 10) & 15, l = (gid >> 14) & 3, tab = gid >> 16;
  const float* W = (tab ? pqw : pkw) + (size_t)l * 65536;
  const float* Bb = (tab ? pqb : pkb) + (size_t)l * 256;
  int col = (ch >> 3) * 128 + (ch & 7) * 16 + d;
  float s = Bb[col];
  const float* per = pe + (size_t)z * 256;
  for (int kk = 0; kk < 256; kk++) s += per[kk] * W[(size_t)kk * 256 + col];
  u16* dst = tab ? pqfsw : pkfsw;
  dst[(((size_t)l * 16 + ch) * 64 + z) * 16 + d] = f2b(s);
}

// ---------------- MFMA GEMM, BMx64, BK=64, 4 waves (BM/2 x 32 each), LDS dbuf, T2 swizzle ----------------
template <int EPI, int BM>
__global__ __launch_bounds__(256) void k_gemm(const u16* A, const u16* W, int K,
                                              const float* bias0, const float* bias1, const float* bias2,
                                              void* out0, void* out1, void* out2) {
  constexpr int WROWS = BM / 2;        // rows per wave m-half
  constexpr int FI = WROWS / 16;       // a-fragments per wave
  constexpr int ACH = BM / 32;         // A stage chunks per thread (2 or 4)
  __shared__ u16 As[2][BM * 64];
  __shared__ u16 Bs[2][4096];
  int w = threadIdx.x >> 6, lane = threadIdx.x & 63;
  int la = lane & 15, lg = lane >> 4;
  int wm = w & 1, wn = w >> 1;
  int m0 = blockIdx.x * BM;
  int n0 = blockIdx.y * 64;
  v4f acc[FI][2] = {};
  int nt = K >> 6;
#define STAGE(kb, buf) do {                                                      \
    _Pragma("unroll")                                                            \
    for (int p_ = 0; p_ < ACH; p_++) {                                           \
      int e_ = threadIdx.x + p_ * 256;                                           \
      int row_ = e_ >> 3, ch_ = e_ & 7;                                          \
      int sk_ = (ch_ ^ (row_ & 7)) * 8;                                          \
      gload16(A + (size_t)(m0 + row_) * K + (kb) + sk_, &As[buf][e_ * 8]);       \
    }                                                                            \
    _Pragma("unroll")                                                            \
    for (int p_ = 0; p_ < 2; p_++) {                                             \
      int e_ = threadIdx.x + p_ * 256;                                           \
      int row_ = e_ >> 3, ch_ = e_ & 7;                                          \
      int sk_ = (ch_ ^ (row_ & 7)) * 8;                                          \
      gload16(W + (size_t)(n0 + row_) * K + (kb) + sk_, &Bs[buf][e_ * 8]);       \
    }                                                                            \
  } while (0)
  STAGE(0, 0);
  __syncthreads();
  for (int t = 0; t < nt; t++) {
    int cur = t & 1;
    if (t + 1 < nt) STAGE((t + 1) << 6, cur ^ 1);
    const u16* as = As[cur];
    const u16* bs = Bs[cur];
#pragma unroll
    for (int ks = 0; ks < 2; ks++) {
      v8bf af[FI];
#pragma unroll
      for (int fi = 0; fi < FI; fi++) {
        int ra = wm * WROWS + fi * 16 + la;
        af[fi] = ldg8(as + ra * 64 + ((ks * 32 + lg * 8) ^ ((ra & 7) << 3)));
      }
      int rb0 = wn * 32 + la, rb1 = wn * 32 + 16 + la;
      v8bf b0 = ldg8(bs + rb0 * 64 + ((ks * 32 + lg * 8) ^ ((rb0 & 7) << 3)));
      v8bf b1 = ldg8(bs + rb1 * 64 + ((ks * 32 + lg * 8) ^ ((rb1 & 7) << 3)));
#pragma unroll
      for (int fi = 0; fi < FI; fi++) {
        acc[fi][0] = __builtin_amdgcn_mfma_f32_16x16x32_bf16(af[fi], b0, acc[fi][0], 0, 0, 0);
        acc[fi][1] = __builtin_amdgcn_mfma_f32_16x16x32_bf16(af[fi], b1, acc[fi][1], 0, 0, 0);
      }
    }
    __syncthreads();
  }
#undef STAGE
#pragma unroll
  for (int fi = 0; fi < FI; fi++)
#pragma unroll
    for (int fj = 0; fj < 2; fj++)
#pragma unroll
      for (int rr = 0; rr < 4; rr++) {
        int m = m0 + wm * WROWS + fi * 16 + lg * 4 + rr;
        int n = n0 + wn * 32 + fj * 16 + la;
        float v = acc[fi][fj][rr];
        if (EPI == 0) {
          const float* bp = (n < 256 ? bias0 : n < 512 ? bias1 : bias2);
          v += bp[n & 255];
          int b = m >> 9, i = m & 511, h = (n & 255) >> 5, d = n & 31;
          if (n < 512) {
            u16* dst = (u16*)(n < 256 ? out0 : out1);
            dst[(((size_t)(b * 8 + h)) * NPAD + i) * 32 + d] = f2b(v);
          } else {
            ((u16*)out2)[(((size_t)(b * 8 + h)) * 32 + d) * NPAD + i] = f2b(v);
          }
        } else if (EPI == 1) {
          ((u16*)out0)[(size_t)m * 256 + n] = f2b(v + bias0[n]);
        } else {
          float x = v + bias0[n];
          float g = 0.5f * x * (1.0f + erff(x * 0.70710678118654752f));
          ((u16*)out0)[(size_t)m * 512 + n] = f2b(g);
        }
      }
}

// ---------------- out-proj GEMM with fused attention-combine A-staging (BK=64, swizzled) ----------------
__global__ __launch_bounds__(256) void k_gemmA(const u16* opartb, const float* lpart,
                                               const u16* W, const float* bias, u16* y16) {
  __shared__ u16 As[2][4096];
  __shared__ u16 Bs[2][4096];
  int w = threadIdx.x >> 6, lane = threadIdx.x & 63;
  int la = lane & 15, lg = lane >> 4;
  int wm = w & 1, wn = w >> 1;
  int m0 = blockIdx.x * 64;
  int n0 = blockIdx.y * 64;
  v4f acc[2][2] = {};
#define STAGE_A(tt, buf) do {                                                            \
    _Pragma("unroll")                                                                    \
    for (int p_ = 0; p_ < 2; p_++) {                                                     \
      int e_ = threadIdx.x + p_ * 256;                                                   \
      int row_ = e_ >> 3, ch_ = e_ & 7;                                                  \
      int h_ = 2 * (tt) + (ch_ >> 2), dq_ = (ch_ & 3) * 8;                               \
      int m_ = m0 + row_, bb_ = m_ >> 9, ii_ = m_ & 511;                                 \
      size_t rb_ = ((size_t)(bb_ * 8 + h_)) * NPAD + ii_;                                \
      float l_ = lpart[rb_] + lpart[NROWS + rb_] + lpart[2u * NROWS + rb_] + lpart[3u * NROWS + rb_]; \
      float inv_ = 1.0f / l_;                                                            \
      u16x8 a0_ = *(const u16x8*)(opartb + rb_ * 32 + dq_);                              \
      u16x8 a1_ = *(const u16x8*)(opartb + ((size_t)NROWS + rb_) * 32 + dq_);            \
      u16x8 a2_ = *(const u16x8*)(opartb + ((size_t)2u * NROWS + rb_) * 32 + dq_);       \
      u16x8 a3_ = *(const u16x8*)(opartb + ((size_t)3u * NROWS + rb_) * 32 + dq_);       \
      u16x8 r_;                                                                          \
      _Pragma("unroll")                                                                  \
      for (int e2 = 0; e2 < 8; e2++)                                                     \
        r_[e2] = f2b((b2f(a0_[e2]) + b2f(a1_[e2]) + b2f(a2_[e2]) + b2f(a3_[e2])) * inv_);\
      *(u16x8*)(&As[buf][row_ * 64 + ((ch_ ^ (row_ & 7)) * 8)]) = r_;                    \
    }                                                                                    \
  } while (0)
#define STAGE_B(kb, buf) do {                                                    \
    _Pragma("unroll")                                                            \
    for (int p_ = 0; p_ < 2; p_++) {                                             \
      int e_ = threadIdx.x + p_ * 256;                                           \
      int row_ = e_ >> 3, ch_ = e_ & 7;                                          \
      int sk_ = (ch_ ^ (row_ & 7)) * 8;                                          \
      gload16(W + (size_t)(n0 + row_) * 256 + (kb) + sk_, &Bs[buf][e_ * 8]);     \
    }                                                                            \
  } while (0)
  STAGE_A(0, 0);
  STAGE_B(0, 0);
  __syncthreads();
  for (int t = 0; t < 4; t++) {
    int cur = t & 1;
    if (t + 1 < 4) {
      STAGE_A(t + 1, cur ^ 1);
      STAGE_B((t + 1) << 6, cur ^ 1);
    }
    const u16* as = As[cur];
    const u16* bs = Bs[cur];
#pragma unroll
    for (int ks = 0; ks < 2; ks++) {
      int ra0 = wm * 32 + la, ra1 = wm * 32 + 16 + la;
      int rb0 = wn * 32 + la, rb1 = wn * 32 + 16 + la;
      v8bf a0 = ldg8(as + ra0 * 64 + ((ks * 32 + lg * 8) ^ ((ra0 & 7) << 3)));
      v8bf a1 = ldg8(as + ra1 * 64 + ((ks * 32 + lg * 8) ^ ((ra1 & 7) << 3)));
      v8bf b0 = ldg8(bs + rb0 * 64 + ((ks * 32 + lg * 8) ^ ((rb0 & 7) << 3)));
      v8bf b1 = ldg8(bs + rb1 * 64 + ((ks * 32 + lg * 8) ^ ((rb1 & 7) << 3)));
      acc[0][0] = __builtin_amdgcn_mfma_f32_16x16x32_bf16(a0, b0, acc[0][0], 0, 0, 0);
      acc[0][1] = __builtin_amdgcn_mfma_f32_16x16x32_bf16(a0, b1, acc[0][1], 0, 0, 0);
      acc[1][0] = __builtin_amdgcn_mfma_f32_16x16x32_bf16(a1, b0, acc[1][0], 0, 0, 0);
      acc[1][1] = __builtin_amdgcn_mfma_f32_16x16x32_bf16(a1, b1, acc[1][1], 0, 0, 0);
    }
    __syncthreads();
  }
#undef STAGE_A
#undef STAGE_B
#pragma unroll
  for (int fi = 0; fi < 2; fi++)
#pragma unroll
    for (int fj = 0; fj < 2; fj++)
#pragma unroll
      for (int rr = 0; rr < 4; rr++) {
        int mm = m0 + wm * 32 + fi * 16 + lg * 4 + rr;
        int n = n0 + wn * 32 + fj * 16 + la;
        y16[(size_t)mm * 256 + n] = f2b(acc[fi][fj][rr] + bias[n]);
      }
}

// ---------------- pos tables (merged, vector stores): z=0 -> tabC2; z=1 -> tabP2 ----------------
__global__ __launch_bounds__(256) void k_tab(const u16* qh, const u16* kh,
                                             const u16* pkfsw, const u16* pqfsw,
                                             u16* tabC2, u16* tabP2, int l) {
  __shared__ __align__(16) u16 qs[4][8][32];
  const u16* srcp = blockIdx.z ? kh : qh;
  const u16* tbl = blockIdx.z ? pqfsw : pkfsw;
  u16* dst = blockIdx.z ? tabP2 : tabC2;
  int b = blockIdx.y, i0 = blockIdx.x * 4;
  int t = threadIdx.x;
  {
    int flat = t * 4;
    int si = flat >> 8, sh = (flat >> 5) & 7, sd = flat & 31;
    *(u16x4*)&qs[si][sh][sd] =
        *(const u16x4*)(srcp + (((size_t)(b * 8 + sh)) * NPAD + i0 + si) * 32 + sd);
  }
  __syncthreads();
  int z = t & 63, cg = t >> 6;
  u16x8 W0[4], W1[4];
#pragma unroll
  for (int cc = 0; cc < 4; cc++) {
    int ch = cg * 4 + cc;
    const u16* pp = tbl + (((size_t)l * 16 + ch) * 64 + z) * 16;
    W0[cc] = *(const u16x8*)pp;
    W1[cc] = *(const u16x8*)(pp + 8);
  }
#pragma unroll
  for (int ii = 0; ii < 4; ii++) {
    u16x4 res;
#pragma unroll
    for (int cc = 0; cc < 4; cc++) {
      int ch = cg * 4 + cc, c = ch >> 3, h = ch & 7;
      const u16* qq = &qs[ii][h][c * 16];
      float s = 0.f;
#pragma unroll
      for (int d = 0; d < 8; d++) s += b2f(qq[d]) * b2f(W0[cc][d]);
#pragma unroll
      for (int d = 0; d < 8; d++) s += b2f(qq[d + 8]) * b2f(W1[cc][d]);
      res[cc] = f2b(s);
    }
    *(u16x4*)&dst[(((size_t)b * NPAD + i0 + ii) * 64 + z) * 16 + cg * 4] = res;
  }
}

// ---------------- fused MFMA attention: single posb phase per part (1 barrier) ----------------
// grid 2048 (XCD-swizzled): b(4b), i-tile(5b), part(2b). parts 0-2: 2 tiles; part 3: tile 6 + j=448.
__global__ __launch_bounds__(512) void k_attn(const u16* qh, const u16* kh, const u16* vtp,
                                              const u16* tabC2, const u16* tabP2, const u16* relp,
                                              u16* opartb, float* lpart) {
  __shared__ u32 posb[4][16][134];           // packed bf16 h-pairs; tile tt at col tt*66
  __shared__ __align__(16) u16 ps[8][16][72];
  int bid = blockIdx.x;
  int idx = (bid & 7) * 256 + (bid >> 3);
  int b = idx >> 7;
  int rest = idx & 127;
  int i0 = (rest >> 2) * 16;
  int part = rest & 3;
  int t = threadIdx.x, w = t >> 6, lane = t & 63;
  int la = lane & 15, lg = lane >> 4;
  v8bf qa = ldg8(qh + (((size_t)(b * 8 + w)) * NPAD + i0 + la) * 32 + lg * 8);
  float lrow[4] = {0.f, 0.f, 0.f, 0.f};
  v4f o0 = {}; v4f o1 = {};
  const float scale = 0.17677669529663687f;
  const float MC = 8.0f;
  const u16* kbase = kh + ((size_t)(b * 8 + w)) * NPAD * 32;
  const u16* vbase = vtp + ((size_t)(b * 8 + w)) * 32 * NPAD;
  const u16* rbase = relp + ((size_t)b * NPAD + i0) * NPAD;
  int ntile = (part == 3) ? 1 : 2;
  // ---- stage ALL posb for this part's tiles, then one barrier ----
  for (int tt = 0; tt < ntile; tt++) {
    int j0 = (part * 2 + tt) * 64;
#pragma unroll
    for (int pp = 0; pp < 2; pp++) {
      int p = t + pp * 512;
      int si = p >> 6, sj = p & 63;
      int ig = i0 + si, jg = j0 + sj;
      float pos[8] = {0.f, 0.f, 0.f, 0.f, 0.f, 0.f, 0.f, 0.f};
      if (ig > 0 && jg > 0) {
        unsigned rp = rbase[(size_t)si * NPAD + jg];
        int zx = rp & 255, zy = rp >> 8;
        u16x8 Av = *(const u16x8*)(tabC2 + (((size_t)b * NPAD + ig) * 64 + zx) * 16);
        u16x8 Cv = *(const u16x8*)(tabP2 + (((size_t)b * NPAD + jg) * 64 + zx) * 16);
        u16x8 Bv = *(const u16x8*)(tabC2 + (((size_t)b * NPAD + ig) * 64 + zy) * 16 + 8);
        u16x8 Dv = *(const u16x8*)(tabP2 + (((size_t)b * NPAD + jg) * 64 + zy) * 16 + 8);
#pragma unroll
        for (int h = 0; h < 8; h++)
          pos[h] = (b2f(Av[h]) + b2f(Cv[h])) + (b2f(Bv[h]) + b2f(Dv[h]));
      }
#pragma unroll
      for (int hp = 0; hp < 4; hp++)
        posb[hp][si][tt * 66 + sj] = (u32)f2b(pos[2 * hp]) | ((u32)f2b(pos[2 * hp + 1]) << 16);
    }
  }
  __syncthreads();
  // ---- compute both tiles (ps is wave-private: no barriers needed) ----
  for (int tt = 0; tt < ntile; tt++) {
    int j0 = (part * 2 + tt) * 64;
    v4f s[4];
#pragma unroll
    for (int fj = 0; fj < 4; fj++) {
      v8bf kf = ldg8(kbase + (size_t)(j0 + fj * 16 + la) * 32 + lg * 8);
      v4f zero = {};
      s[fj] = __builtin_amdgcn_mfma_f32_16x16x32_bf16(qa, kf, zero, 0, 0, 0);
    }
    float pvv[4][4];
    int wsel = (w & 1) ? 16 : 0;
#pragma unroll
    for (int fj = 0; fj < 4; fj++) {
#pragma unroll
      for (int rr = 0; rr < 4; rr++) {
        int il = lg * 4 + rr;
        u32 pk = posb[w >> 1][il][tt * 66 + fj * 16 + la];
        float posv = b2f((u16)(pk >> wsel));
        float lv = (s[fj][rr] + posv) * scale;
        pvv[fj][rr] = __expf(lv - MC);
      }
    }
#pragma unroll
    for (int rr = 0; rr < 4; rr++)
      lrow[rr] += pvv[0][rr] + pvv[1][rr] + pvv[2][rr] + pvv[3][rr];
#pragma unroll
    for (int fj = 0; fj < 4; fj++)
#pragma unroll
      for (int rr = 0; rr < 4; rr++)
        ps[w][lg * 4 + rr][fj * 16 + la] = f2b(pvv[fj][rr]);
    v8bf pa0 = __builtin_bit_cast(v8bf, *(const u16x8*)&ps[w][la][lg * 8]);
    v8bf pa1 = __builtin_bit_cast(v8bf, *(const u16x8*)&ps[w][la][32 + lg * 8]);
    v8bf v00 = ldg8(vbase + (size_t)la * NPAD + j0 + lg * 8);
    v8bf v01 = ldg8(vbase + (size_t)la * NPAD + j0 + 32 + lg * 8);
    v8bf v10 = ldg8(vbase + (size_t)(16 + la) * NPAD + j0 + lg * 8);
    v8bf v11 = ldg8(vbase + (size_t)(16 + la) * NPAD + j0 + 32 + lg * 8);
    o0 = __builtin_amdgcn_mfma_f32_16x16x32_bf16(pa0, v00, o0, 0, 0, 0);
    o0 = __builtin_amdgcn_mfma_f32_16x16x32_bf16(pa1, v01, o0, 0, 0, 0);
    o1 = __builtin_amdgcn_mfma_f32_16x16x32_bf16(pa0, v10, o1, 0, 0, 0);
    o1 = __builtin_amdgcn_mfma_f32_16x16x32_bf16(pa1, v11, o1, 0, 0, 0);
  }
  if (part == 3) {
    v8bf kf = ldg8(kbase + (size_t)448 * 32 + lg * 8);
    float dot = 0.f;
#pragma unroll
    for (int e = 0; e < 8; e++) dot += (float)qa[e] * (float)kf[e];
    dot += __shfl_xor(dot, 16);
    dot += __shfl_xor(dot, 32);
    int ig = i0 + la;
    float pos = 0.f;
    if (ig > 0) {
      unsigned rp = relp[((size_t)b * NPAD + ig) * NPAD + 448];
      int zx = rp & 255, zy = rp >> 8;
      pos = b2f(tabC2[(((size_t)b * NPAD + ig) * 64 + zx) * 16 + w])
          + b2f(tabP2[(((size_t)b * NPAD + 448) * 64 + zx) * 16 + w])
          + b2f(tabC2[(((size_t)b * NPAD + ig) * 64 + zy) * 16 + 8 + w])
          + b2f(tabP2[(((size_t)b * NPAD + 448) * 64 + zy) * 16 + 8 + w]);
    }
    float p448 = __expf((dot + pos) * scale - MC);
    float va = b2f(vbase[(size_t)la * NPAD + 448]);
    float vb_ = b2f(vbase[(size_t)(16 + la) * NPAD + 448]);
#pragma unroll
    for (int rr = 0; rr < 4; rr++) {
      float pr = __shfl(p448, lg * 4 + rr);
      o0[rr] += pr * va;
      o1[rr] += pr * vb_;
      if (la == 0) lrow[rr] += pr;
    }
  }
#pragma unroll
  for (int rr = 0; rr < 4; rr++) {
    float l = lrow[rr];
    l += __shfl_xor(l, 1); l += __shfl_xor(l, 2); l += __shfl_xor(l, 4); l += __shfl_xor(l, 8);
    int ig = i0 + lg * 4 + rr;
    size_t row = (size_t)part * NROWS + (((size_t)(b * 8 + w)) * NPAD + ig);
    opartb[row * 32 + la] = f2b(o0[rr]);
    opartb[row * 32 + 16 + la] = f2b(o1[rr]);
    if (la == 0) lpart[row] = l;
  }
}

// ---------------- residual + LayerNorm; LAST=1 writes final output ----------------
template <int LAST>
__global__ __launch_bounds__(256) void k_ln(float* xf, u16* xb, const u16* y16,
                                            const float* resv, int ridx,
                                            const float* g_, const float* b_, float* outp) {
  int row = blockIdx.x * 4 + (threadIdx.x >> 6);
  int lane = threadIdx.x & 63;
  float res = resv[ridx];
  const u16* yr = y16 + (size_t)row * DD;
  float* xr = xf + (size_t)row * DD;
  int c = lane * 4;
  float4 xv = *(const float4*)(xr + c);
  u16x4 yv = *(const u16x4*)(yr + c);
  float v0 = xv.x + b2f(yv[0]) * res, v1 = xv.y + b2f(yv[1]) * res;
  float v2 = xv.z + b2f(yv[2]) * res, v3 = xv.w + b2f(yv[3]) * res;
  float sum = v0 + v1 + v2 + v3;
  sum += __shfl_xor(sum, 1); sum += __shfl_xor(sum, 2); sum += __shfl_xor(sum, 4);
  sum += __shfl_xor(sum, 8); sum += __shfl_xor(sum, 16); sum += __shfl_xor(sum, 32);
  float mean = sum * (1.0f / 256.0f);
  float d0 = v0 - mean, d1 = v1 - mean, d2 = v2 - mean, d3 = v3 - mean;
  float vs = d0 * d0 + d1 * d1 + d2 * d2 + d3 * d3;
  vs += __shfl_xor(vs, 1); vs += __shfl_xor(vs, 2); vs += __shfl_xor(vs, 4);
  vs += __shfl_xor(vs, 8); vs += __shfl_xor(vs, 16); vs += __shfl_xor(vs, 32);
  float rstd = rsqrtf(vs * (1.0f / 256.0f) + 1e-5f);
  float o0 = d0 * rstd * g_[c + 0] + b_[c + 0];
  float o1 = d1 * rstd * g_[c + 1] + b_[c + 1];
  float o2 = d2 * rstd * g_[c + 2] + b_[c + 2];
  float o3 = d3 * rstd * g_[c + 3] + b_[c + 3];
  if (!LAST) {
    *(float4*)(xr + c) = make_float4(o0, o1, o2, o3);
    u16x4 bv; bv[0] = f2b(o0); bv[1] = f2b(o1); bv[2] = f2b(o2); bv[3] = f2b(o3);
    *(u16x4*)(xb + (size_t)row * DD + c) = bv;
  } else {
    int bq = row >> 9, r = row & 511;
    if (r >= 1) {
      int p = r - 1;
      float4 val = (p < 448) ? make_float4(o0, o1, o2, o3) : make_float4(0.f, 0.f, 0.f, 0.f);
      *(float4*)(outp + ((size_t)bq * PP + p) * DD + c) = val;
    } else {
      *(float4*)(outp + ((size_t)bq * PP + 511) * DD + c) = make_float4(0.f, 0.f, 0.f, 0.f);
    }
  }
}

__global__ void k_diag(float* out, int v) {
  int gid = blockIdx.x * 64 + threadIdx.x;
  float4 r = make_float4(0.f, 0.f, 0.f, 0.f);
  if (gid == 28672) r.x = (float)v;
  *(float4*)(out + (size_t)gid * 4) = r;
}

extern "C" void kernel_launch(void* const* d_in, const int* in_sizes, int n_in,
                              void* d_out, int out_size, void* d_ws, size_t ws_size,
                              hipStream_t stream) {
  const float* embeds = (const float*)d_in[0];
  const float* xmin = (const float*)d_in[1];
  const float* xmax = (const float*)d_in[2];
  const float* ymin = (const float*)d_in[3];
  const float* ymax = (const float*)d_in[4];
  const float* width = (const float*)d_in[5];
  const float* height = (const float*)d_in[6];
  const float* empty_embed = (const float*)d_in[7];
  const float* pos_emb = (const float*)d_in[8];
  const float* cq_w = (const float*)d_in[9];
  const float* cq_b = (const float*)d_in[10];
  const float* ck_w = (const float*)d_in[11];
  const float* ck_b = (const float*)d_in[12];
  const float* pk_w = (const float*)d_in[13];
  const float* pk_b = (const float*)d_in[14];
  const float* pq_w = (const float*)d_in[15];
  const float* pq_b = (const float*)d_in[16];
  const float* cv_w = (const float*)d_in[17];
  const float* cv_b = (const float*)d_in[18];
  const float* out_w = (const float*)d_in[19];
  const float* out_b = (const float*)d_in[20];
  const float* res1 = (const float*)d_in[21];
  const float* res2 = (const float*)d_in[22];
  const float* ln1_g = (const float*)d_in[23];
  const float* ln1_b = (const float*)d_in[24];
  const float* ln2_g = (const float*)d_in[25];
  const float* ln2_b = (const float*)d_in[26];
  const float* ff1_w = (const float*)d_in[27];
  const float* ff1_b = (const float*)d_in[28];
  const float* ff2_w = (const float*)d_in[29];
  const float* ff2_b = (const float*)d_in[30];
  const int* page_ids = (const int*)d_in[31];

  char* ws = (char*)d_ws;
  size_t off = 0;
  auto alloc = [&](size_t bytes) -> void* {
    void* p = ws + off;
    off += (bytes + 255) & ~(size_t)255;
    return p;
  };
  float* xf = (float*)alloc((size_t)MM * DD * 4);
  u16* xb = (u16*)alloc((size_t)MM * DD * 2);
  u16* qh = (u16*)alloc((size_t)MM * DD * 2);
  u16* kh = (u16*)alloc((size_t)MM * DD * 2);
  u16* vt = (u16*)alloc((size_t)MM * DD * 2);
  u16* y16 = (u16*)alloc((size_t)MM * DD * 2);
  u16* h1b = (u16*)alloc((size_t)MM * 512 * 2);
  u16* tabC2 = (u16*)alloc((size_t)BB * NPAD * 64 * 16 * 2);
  u16* tabP2 = (u16*)alloc((size_t)BB * NPAD * 64 * 16 * 2);
  u16* relp = (u16*)alloc((size_t)BB * NPAD * NPAD * 2);
  u16* opartb = (u16*)alloc((size_t)4 * NROWS * 32 * 2);
  float* lpart = (float*)alloc((size_t)4 * NROWS * 4);
  u16* wT = (u16*)alloc((size_t)4 * 524288 * 2);
  u16* pkfsw = (u16*)alloc((size_t)4 * 16 * 64 * 16 * 2);
  u16* pqfsw = (u16*)alloc((size_t)4 * 16 * 64 * 16 * 2);
  float* gcx = (float*)alloc((size_t)BB * PP * 4);
  float* gcy = (float*)alloc((size_t)BB * PP * 4);
  float* gw = (float*)alloc((size_t)BB * PP * 4);
  float* gh_ = (float*)alloc((size_t)BB * PP * 4);
  (void)in_sizes; (void)n_in; (void)out_size;

  if (off > ws_size) {
    k_diag<<<dim3(8192), 64, 0, stream>>>((float*)d_out, 216);
    return;
  }

  k_prep<<<dim3(8192), 64, 0, stream>>>(embeds, xmin, xmax, ymin, ymax, width, height,
                                        empty_embed, page_ids, xf, xb, gcx, gcy, gw, gh_);
  k_rel<<<dim3(8192), 64, 0, stream>>>(gcx, gcy, gw, gh_, relp);
  k_wT<<<dim3(2048), 256, 0, stream>>>(cq_w, ck_w, cv_w, out_w, ff1_w, ff2_w, wT);
  k_posproj<<<dim3(512), 256, 0, stream>>>(pos_emb, pk_w, pk_b, pq_w, pq_b, pkfsw, pqfsw);

  for (int l = 0; l < 4; l++) {
    const u16* wl = wT + (size_t)l * 524288;
    k_gemm<0, 128><<<dim3(64, 12), 256, 0, stream>>>(xb, wl, 256, cq_b + l * 256, ck_b + l * 256,
                                                     cv_b + l * 256, qh, kh, vt);
    k_tab<<<dim3(128, 16, 2), 256, 0, stream>>>(qh, kh, pkfsw, pqfsw, tabC2, tabP2, l);
    k_attn<<<dim3(2048), 512, 0, stream>>>(qh, kh, vt, tabC2, tabP2, relp, opartb, lpart);
    k_gemmA<<<dim3(128, 4), 256, 0, stream>>>(opartb, lpart, wl + 196608, out_b + l * 256, y16);
    k_ln<0><<<dim3(2048), 256, 0, stream>>>(xf, xb, y16, res1, l, ln1_g + l * 256, ln1_b + l * 256,
                                            (float*)d_out);
    k_gemm<2, 128><<<dim3(64, 8), 256, 0, stream>>>(xb, wl + 262144, 256, ff1_b + l * 512,
                                                    nullptr, nullptr, h1b, nullptr, nullptr);
    k_gemm<1, 64><<<dim3(128, 4), 256, 0, stream>>>(h1b, wl + 393216, 512, ff2_b + l * 256,
                                                    nullptr, nullptr, y16, nullptr, nullptr);
    if (l < 3)
      k_ln<0><<<dim3(2048), 256, 0, stream>>>(xf, xb, y16, res2, l, ln2_g + l * 256,
                                              ln2_b + l * 256, (float*)d_out);
    else
      k_ln<1><<<dim3(2048), 256, 0, stream>>>(xf, xb, y16, res2, l, ln2_g + l * 256,
                                              ln2_b + l * 256, (float*)d_out);
  }
}

// Round 20
// 501.718 us; speedup vs baseline: 1.0782x; 1.0782x over previous
//
#include <hip/hip_runtime.h>
#include <math.h>

#define BB 16
#define PP 512
#define DD 256
#define HH 8
#define NPAD 512
#define NVAL 449
#define MM (BB*PP)   // 8192
#define NROWS (BB*HH*NPAD)  // 65536

typedef unsigned short u16;
typedef unsigned u32;
typedef __bf16 v8bf __attribute__((ext_vector_type(8)));
typedef float v4f __attribute__((ext_vector_type(4)));
typedef unsigned short u16x8 __attribute__((ext_vector_type(8)));
typedef unsigned short u16x4 __attribute__((ext_vector_type(4)));

static __device__ __forceinline__ float b2f(u16 u) {
  unsigned v = ((unsigned)u) << 16;
  return __builtin_bit_cast(float, v);
}
static __device__ __forceinline__ u16 f2b(float f) {
  unsigned x = __builtin_bit_cast(unsigned, f);
  unsigned lsb = (x >> 16) & 1u;
  x += 0x7fffu + lsb;
  return (u16)(x >> 16);
}
static __device__ __forceinline__ v8bf ldg8(const u16* p) {
  u16x8 u = *(const u16x8*)p;
  return __builtin_bit_cast(v8bf, u);
}
static __device__ __forceinline__ void gload16(const u16* g, u16* l) {
  __builtin_amdgcn_global_load_lds(
      (__attribute__((address_space(1))) void*)(g),
      (__attribute__((address_space(3))) void*)(l), 16, 0, 0);
}

// ---------------- prep: gather x rows + geometry ----------------
__global__ void k_prep(const float* embeds, const float* xmin, const float* xmax,
                       const float* ymin, const float* ymax, const float* width,
                       const float* height, const float* empty_embed, const int* page_ids,
                       float* xf, u16* xb, float* gcx, float* gcy, float* gw, float* gh_) {
  int bx = blockIdx.x;            // 8192 = b*512 + r
  int b = bx >> 9, r = bx & 511;
  int t = threadIdx.x;            // 64
  int c0 = t * 4;
  const float* src = nullptr;
  if (r == 0) src = empty_embed;
  else if (r <= 448) {
    int gi = page_ids[b * PP + (r - 1)];
    src = embeds + (size_t)gi * DD;
  }
  float4 fv = make_float4(0.f, 0.f, 0.f, 0.f);
  if (src) fv = *(const float4*)(src + c0);
  size_t row = (size_t)b * NPAD + r;
  *(float4*)(xf + row * DD + c0) = fv;
  u16x4 bv; bv[0] = f2b(fv.x); bv[1] = f2b(fv.y); bv[2] = f2b(fv.z); bv[3] = f2b(fv.w);
  *(u16x4*)(xb + row * DD + c0) = bv;
  if (t == 0) {
    int p = r;
    int gi = page_ids[b * PP + p];
    float cx = 0.f, cy = 0.f, ww = 1.f, hh = 1.f;
    if (gi >= 0) {
      cx = 0.5f * (xmin[gi] + xmax[gi]);
      cy = 0.5f * (ymin[gi] + ymax[gi]);
      ww = fmaxf(width[gi], 1e-3f);
      hh = fmaxf(height[gi], 1e-3f);
    }
    gcx[b * PP + p] = cx; gcy[b * PP + p] = cy;
    gw[b * PP + p] = ww;  gh_[b * PP + p] = hh;
  }
}

// ---------------- rel indices (once): relp[b][i][j] = zx | zy<<8 ----------------
__global__ __launch_bounds__(64) void k_rel(const float* gcx, const float* gcy,
                                            const float* gw, const float* gh_, u16* relp) {
  int bx = blockIdx.x;            // 8192 = b*512 + i
  int b = bx >> 9, i = bx & 511;
  int t = threadIdx.x;
  float cxi = 0.f, cyi = 0.f, wi = 1.f, hi = 1.f;
  if (i > 0) {
    cxi = gcx[b * PP + i - 1]; cyi = gcy[b * PP + i - 1];
    wi = gw[b * PP + i - 1];   hi = gh_[b * PP + i - 1];
  }
  u16* dst = relp + ((size_t)b * NPAD + i) * NPAD;
#pragma unroll
  for (int jj = 0; jj < 8; jj++) {
    int j = jj * 64 + t;
    u16 pk = (u16)(32 | (32 << 8));
    if (j > 0) {
      float cxj = gcx[b * PP + j - 1], cyj = gcy[b * PP + j - 1];
      float dxf = rintf((cxj - cxi) / wi);
      float dyf = rintf((cyj - cyi) / hi);
      int zx = (int)(fminf(fmaxf(dxf, -32.f), 31.f)) + 32;
      int zy = (int)(fminf(fmaxf(dyf, -32.f), 31.f)) + 32;
      pk = (u16)(zx | (zy << 8));
    }
    dst[j] = pk;
  }
}

// ---------------- weight transposes (once) ----------------
__global__ __launch_bounds__(256) void k_wT(const float* cq, const float* ck, const float* cv,
                                            const float* ow, const float* f1, const float* f2,
                                            u16* wT) {
  __shared__ u16 lds[32][33];
  int bx = blockIdx.x;           // 2048
  int l = bx >> 9, r = bx & 511;
  const float* src; int N, k0, n0; u16* dst; int dstStride;
  if (r < 192) {
    int mat = r / 64, rr = r % 64;
    k0 = (rr >> 3) * 32; n0 = (rr & 7) * 32;
    src = (mat == 0 ? cq : mat == 1 ? ck : cv) + (size_t)l * 65536;
    N = 256; dst = wT + (size_t)l * 524288 + mat * 65536; dstStride = 256;
  } else if (r < 256) {
    int rr = r - 192;
    k0 = (rr >> 3) * 32; n0 = (rr & 7) * 32;
    src = ow + (size_t)l * 65536; N = 256;
    dst = wT + (size_t)l * 524288 + 196608; dstStride = 256;
  } else if (r < 384) {
    int rr = r - 256;
    k0 = (rr >> 4) * 32; n0 = (rr & 15) * 32;
    src = f1 + (size_t)l * 131072; N = 512;
    dst = wT + (size_t)l * 524288 + 262144; dstStride = 256;
  } else {
    int rr = r - 384;
    k0 = (rr >> 3) * 32; n0 = (rr & 7) * 32;
    src = f2 + (size_t)l * 131072; N = 256;
    dst = wT + (size_t)l * 524288 + 393216; dstStride = 512;
  }
  int tx = threadIdx.x & 31, ty = threadIdx.x >> 5;
#pragma unroll
  for (int yy = 0; yy < 4; yy++) {
    int y = ty + yy * 8;
    lds[y][tx] = f2b(src[(size_t)(k0 + y) * N + n0 + tx]);
  }
  __syncthreads();
#pragma unroll
  for (int yy = 0; yy < 4; yy++) {
    int y = ty + yy * 8;
    dst[(size_t)(n0 + y) * dstStride + k0 + tx] = lds[tx][y];
  }
}

// ---------------- position projections: [L][16 ch][64 z][16 d] bf16, ch=c*8+h ----------------
__global__ __launch_bounds__(256) void k_posproj(const float* pe, const float* pkw, const float* pkb,
                                                 const float* pqw, const float* pqb,
                                                 u16* pkfsw, u16* pqfsw) {
  int gid = blockIdx.x * 256 + threadIdx.x;   // 131072
  int d = gid & 15, z = (gid >> 4) & 63, ch = (gid >> 10) & 15, l = (gid >> 14) & 3, tab = gid >> 16;
  const float* W = (tab ? pqw : pkw) + (size_t)l * 65536;
  const float* Bb = (tab ? pqb : pkb) + (size_t)l * 256;
  int col = (ch >> 3) * 128 + (ch & 7) * 16 + d;
  float s = Bb[col];
  const float* per = pe + (size_t)z * 256;
  for (int kk = 0; kk < 256; kk++) s += per[kk] * W[(size_t)kk * 256 + col];
  u16* dst = tab ? pqfsw : pkfsw;
  dst[(((size_t)l * 16 + ch) * 64 + z) * 16 + d] = f2b(s);
}

// ---------------- MFMA GEMM, BM=64 BN=64 BK=64, 4 waves 2x2, LDS dbuf, T2 swizzle ----------------
template <int EPI>
__global__ __launch_bounds__(256) void k_gemm(const u16* A, const u16* W, int K,
                                              const float* bias0, const float* bias1, const float* bias2,
                                              void* out0, void* out1, void* out2) {
  __shared__ u16 As[2][4096];   // [64][64]
  __shared__ u16 Bs[2][4096];
  int w = threadIdx.x >> 6, lane = threadIdx.x & 63;
  int la = lane & 15, lg = lane >> 4;
  int wm = w & 1, wn = w >> 1;
  int m0 = blockIdx.x * 64;
  int n0 = blockIdx.y * 64;
  v4f acc[2][2] = {};
  int nt = K >> 6;
#define STAGE(kb, buf) do {                                                      \
    _Pragma("unroll")                                                            \
    for (int p_ = 0; p_ < 2; p_++) {                                             \
      int e_ = threadIdx.x + p_ * 256;                                           \
      int row_ = e_ >> 3, ch_ = e_ & 7;                                          \
      int sk_ = (ch_ ^ (row_ & 7)) * 8;                                          \
      gload16(A + (size_t)(m0 + row_) * K + (kb) + sk_, &As[buf][e_ * 8]);       \
      gload16(W + (size_t)(n0 + row_) * K + (kb) + sk_, &Bs[buf][e_ * 8]);       \
    }                                                                            \
  } while (0)
  STAGE(0, 0);
  __syncthreads();
  for (int t = 0; t < nt; t++) {
    int cur = t & 1;
    if (t + 1 < nt) STAGE((t + 1) << 6, cur ^ 1);
    const u16* as = As[cur];
    const u16* bs = Bs[cur];
#pragma unroll
    for (int ks = 0; ks < 2; ks++) {
      int ra0 = wm * 32 + la, ra1 = wm * 32 + 16 + la;
      int rb0 = wn * 32 + la, rb1 = wn * 32 + 16 + la;
      v8bf a0 = ldg8(as + ra0 * 64 + ((ks * 32 + lg * 8) ^ ((ra0 & 7) << 3)));
      v8bf a1 = ldg8(as + ra1 * 64 + ((ks * 32 + lg * 8) ^ ((ra1 & 7) << 3)));
      v8bf b0 = ldg8(bs + rb0 * 64 + ((ks * 32 + lg * 8) ^ ((rb0 & 7) << 3)));
      v8bf b1 = ldg8(bs + rb1 * 64 + ((ks * 32 + lg * 8) ^ ((rb1 & 7) << 3)));
      acc[0][0] = __builtin_amdgcn_mfma_f32_16x16x32_bf16(a0, b0, acc[0][0], 0, 0, 0);
      acc[0][1] = __builtin_amdgcn_mfma_f32_16x16x32_bf16(a0, b1, acc[0][1], 0, 0, 0);
      acc[1][0] = __builtin_amdgcn_mfma_f32_16x16x32_bf16(a1, b0, acc[1][0], 0, 0, 0);
      acc[1][1] = __builtin_amdgcn_mfma_f32_16x16x32_bf16(a1, b1, acc[1][1], 0, 0, 0);
    }
    __syncthreads();
  }
#undef STAGE
#pragma unroll
  for (int fi = 0; fi < 2; fi++)
#pragma unroll
    for (int fj = 0; fj < 2; fj++)
#pragma unroll
      for (int rr = 0; rr < 4; rr++) {
        int m = m0 + wm * 32 + fi * 16 + lg * 4 + rr;
        int n = n0 + wn * 32 + fj * 16 + la;
        float v = acc[fi][fj][rr];
        if (EPI == 0) {
          const float* bp = (n < 256 ? bias0 : n < 512 ? bias1 : bias2);
          v += bp[n & 255];
          int b = m >> 9, i = m & 511, h = (n & 255) >> 5, d = n & 31;
          if (n < 512) {
            u16* dst = (u16*)(n < 256 ? out0 : out1);
            dst[(((size_t)(b * 8 + h)) * NPAD + i) * 32 + d] = f2b(v);
          } else {
            ((u16*)out2)[(((size_t)(b * 8 + h)) * 32 + d) * NPAD + i] = f2b(v);
          }
        } else if (EPI == 1) {
          ((u16*)out0)[(size_t)m * 256 + n] = f2b(v + bias0[n]);
        } else {
          float x = v + bias0[n];
          float g = 0.5f * x * (1.0f + erff(x * 0.70710678118654752f));
          ((u16*)out0)[(size_t)m * 512 + n] = f2b(g);
        }
      }
}

// ---------------- pos tables (merged, vector stores): z=0 -> tabC2; z=1 -> tabP2 ----------------
__global__ __launch_bounds__(256) void k_tab(const u16* qh, const u16* kh,
                                             const u16* pkfsw, const u16* pqfsw,
                                             u16* tabC2, u16* tabP2, int l) {
  __shared__ __align__(16) u16 qs[4][8][32];
  const u16* srcp = blockIdx.z ? kh : qh;
  const u16* tbl = blockIdx.z ? pqfsw : pkfsw;
  u16* dst = blockIdx.z ? tabP2 : tabC2;
  int b = blockIdx.y, i0 = blockIdx.x * 4;
  int t = threadIdx.x;
  {
    int flat = t * 4;
    int si = flat >> 8, sh = (flat >> 5) & 7, sd = flat & 31;
    *(u16x4*)&qs[si][sh][sd] =
        *(const u16x4*)(srcp + (((size_t)(b * 8 + sh)) * NPAD + i0 + si) * 32 + sd);
  }
  __syncthreads();
  int z = t & 63, cg = t >> 6;
  u16x8 W0[4], W1[4];
#pragma unroll
  for (int cc = 0; cc < 4; cc++) {
    int ch = cg * 4 + cc;
    const u16* pp = tbl + (((size_t)l * 16 + ch) * 64 + z) * 16;
    W0[cc] = *(const u16x8*)pp;
    W1[cc] = *(const u16x8*)(pp + 8);
  }
#pragma unroll
  for (int ii = 0; ii < 4; ii++) {
    u16x4 res;
#pragma unroll
    for (int cc = 0; cc < 4; cc++) {
      int ch = cg * 4 + cc, c = ch >> 3, h = ch & 7;
      const u16* qq = &qs[ii][h][c * 16];
      float s = 0.f;
#pragma unroll
      for (int d = 0; d < 8; d++) s += b2f(qq[d]) * b2f(W0[cc][d]);
#pragma unroll
      for (int d = 0; d < 8; d++) s += b2f(qq[d + 8]) * b2f(W1[cc][d]);
      res[cc] = f2b(s);
    }
    *(u16x4*)&dst[(((size_t)b * NPAD + i0 + ii) * 64 + z) * 16 + cg * 4] = res;
  }
}

// ---------------- fused MFMA attention: un-split, 7 tiles + j=448 tail, direct updb ----------------
// grid 512 (XCD-swizzled): b(4b) x i-tile(5b). 8 waves = 8 heads.
__global__ __launch_bounds__(512) void k_attn(const u16* qh, const u16* kh, const u16* vtp,
                                              const u16* tabC2, const u16* tabP2, const u16* relp,
                                              u16* updb) {
  __shared__ u32 posb[4][16][68];            // packed bf16 h-pairs
  __shared__ __align__(16) u16 ps[8][16][72];
  int bid = blockIdx.x;
  int idx = (bid & 7) * 64 + (bid >> 3);     // 8 XCD chunks of 64 -> 2 b each
  int b = idx >> 5;
  int i0 = (idx & 31) * 16;
  int t = threadIdx.x, w = t >> 6, lane = t & 63;
  int la = lane & 15, lg = lane >> 4;
  v8bf qa = ldg8(qh + (((size_t)(b * 8 + w)) * NPAD + i0 + la) * 32 + lg * 8);
  float lrow[4] = {0.f, 0.f, 0.f, 0.f};
  v4f o0 = {}; v4f o1 = {};
  const float scale = 0.17677669529663687f;
  const float MC = 8.0f;
  const u16* kbase = kh + ((size_t)(b * 8 + w)) * NPAD * 32;
  const u16* vbase = vtp + ((size_t)(b * 8 + w)) * 32 * NPAD;
  const u16* rbase = relp + ((size_t)b * NPAD + i0) * NPAD;
  u16x8 Av[2], Bv[2], Cv[2], Dv[2];
  bool fval[2];
#define FETCH(J0) do {                                                          \
    _Pragma("unroll")                                                           \
    for (int pp = 0; pp < 2; pp++) {                                            \
      int p_ = t + pp * 512;                                                    \
      int si_ = p_ >> 6, sj_ = p_ & 63;                                         \
      int ig_ = i0 + si_, jg_ = (J0) + sj_;                                     \
      bool v_ = (ig_ > 0 && jg_ > 0);                                           \
      fval[pp] = v_;                                                            \
      if (v_) {                                                                 \
        unsigned rp_ = rbase[(size_t)si_ * NPAD + jg_];                         \
        int zx_ = rp_ & 255, zy_ = rp_ >> 8;                                    \
        Av[pp] = *(const u16x8*)(tabC2 + (((size_t)b * NPAD + ig_) * 64 + zx_) * 16);     \
        Cv[pp] = *(const u16x8*)(tabP2 + (((size_t)b * NPAD + jg_) * 64 + zx_) * 16);     \
        Bv[pp] = *(const u16x8*)(tabC2 + (((size_t)b * NPAD + ig_) * 64 + zy_) * 16 + 8); \
        Dv[pp] = *(const u16x8*)(tabP2 + (((size_t)b * NPAD + jg_) * 64 + zy_) * 16 + 8); \
      }                                                                         \
    }                                                                           \
  } while (0)
  FETCH(0);
  for (int tt = 0; tt < 7; tt++) {
    int j0 = tt * 64;
    // ---- posb write from prefetched regs ----
#pragma unroll
    for (int pp = 0; pp < 2; pp++) {
      int p = t + pp * 512;
      int si = p >> 6, sj = p & 63;
      float pos[8] = {0.f, 0.f, 0.f, 0.f, 0.f, 0.f, 0.f, 0.f};
      if (fval[pp]) {
#pragma unroll
        for (int h = 0; h < 8; h++)
          pos[h] = (b2f(Av[pp][h]) + b2f(Cv[pp][h])) + (b2f(Bv[pp][h]) + b2f(Dv[pp][h]));
      }
#pragma unroll
      for (int hp = 0; hp < 4; hp++)
        posb[hp][si][sj] = (u32)f2b(pos[2 * hp]) | ((u32)f2b(pos[2 * hp + 1]) << 16);
    }
    __syncthreads();
    // ---- QK^T + logits (tiles 0..6: all j <= 447 valid) ----
    v4f s[4];
#pragma unroll
    for (int fj = 0; fj < 4; fj++) {
      v8bf kf = ldg8(kbase + (size_t)(j0 + fj * 16 + la) * 32 + lg * 8);
      v4f zero = {};
      s[fj] = __builtin_amdgcn_mfma_f32_16x16x32_bf16(qa, kf, zero, 0, 0, 0);
    }
    float pvv[4][4];
    int wsel = (w & 1) ? 16 : 0;
#pragma unroll
    for (int fj = 0; fj < 4; fj++) {
#pragma unroll
      for (int rr = 0; rr < 4; rr++) {
        int il = lg * 4 + rr;
        u32 pk = posb[w >> 1][il][fj * 16 + la];
        float posv = b2f((u16)(pk >> wsel));
        float lv = (s[fj][rr] + posv) * scale;
        pvv[fj][rr] = __expf(lv - MC);
      }
    }
    __syncthreads();          // posb consumed
    if (tt + 1 < 7) FETCH(j0 + 64);    // prefetch next tile's gathers under PV
#pragma unroll
    for (int rr = 0; rr < 4; rr++)
      lrow[rr] += pvv[0][rr] + pvv[1][rr] + pvv[2][rr] + pvv[3][rr];
#pragma unroll
    for (int fj = 0; fj < 4; fj++)
#pragma unroll
      for (int rr = 0; rr < 4; rr++)
        ps[w][lg * 4 + rr][fj * 16 + la] = f2b(pvv[fj][rr]);
    v8bf pa0 = __builtin_bit_cast(v8bf, *(const u16x8*)&ps[w][la][lg * 8]);
    v8bf pa1 = __builtin_bit_cast(v8bf, *(const u16x8*)&ps[w][la][32 + lg * 8]);
    v8bf v00 = ldg8(vbase + (size_t)la * NPAD + j0 + lg * 8);
    v8bf v01 = ldg8(vbase + (size_t)la * NPAD + j0 + 32 + lg * 8);
    v8bf v10 = ldg8(vbase + (size_t)(16 + la) * NPAD + j0 + lg * 8);
    v8bf v11 = ldg8(vbase + (size_t)(16 + la) * NPAD + j0 + 32 + lg * 8);
    o0 = __builtin_amdgcn_mfma_f32_16x16x32_bf16(pa0, v00, o0, 0, 0, 0);
    o0 = __builtin_amdgcn_mfma_f32_16x16x32_bf16(pa1, v01, o0, 0, 0, 0);
    o1 = __builtin_amdgcn_mfma_f32_16x16x32_bf16(pa0, v10, o1, 0, 0, 0);
    o1 = __builtin_amdgcn_mfma_f32_16x16x32_bf16(pa1, v11, o1, 0, 0, 0);
  }
#undef FETCH
  {
    // single valid column j=448 (tile 7 is otherwise fully masked)
    v8bf kf = ldg8(kbase + (size_t)448 * 32 + lg * 8);
    float dot = 0.f;
#pragma unroll
    for (int e = 0; e < 8; e++) dot += (float)qa[e] * (float)kf[e];
    dot += __shfl_xor(dot, 16);
    dot += __shfl_xor(dot, 32);
    int ig = i0 + la;
    float pos = 0.f;
    if (ig > 0) {
      unsigned rp = relp[((size_t)b * NPAD + ig) * NPAD + 448];
      int zx = rp & 255, zy = rp >> 8;
      pos = b2f(tabC2[(((size_t)b * NPAD + ig) * 64 + zx) * 16 + w])
          + b2f(tabP2[(((size_t)b * NPAD + 448) * 64 + zx) * 16 + w])
          + b2f(tabC2[(((size_t)b * NPAD + ig) * 64 + zy) * 16 + 8 + w])
          + b2f(tabP2[(((size_t)b * NPAD + 448) * 64 + zy) * 16 + 8 + w]);
    }
    float p448 = __expf((dot + pos) * scale - MC);
    float va = b2f(vbase[(size_t)la * NPAD + 448]);
    float vb_ = b2f(vbase[(size_t)(16 + la) * NPAD + 448]);
#pragma unroll
    for (int rr = 0; rr < 4; rr++) {
      float pr = __shfl(p448, lg * 4 + rr);
      o0[rr] += pr * va;
      o1[rr] += pr * vb_;
      if (la == 0) lrow[rr] += pr;
    }
  }
  // ---- normalize and write directly to updb [b*512+i][h*32+d] ----
#pragma unroll
  for (int rr = 0; rr < 4; rr++) {
    float l = lrow[rr];
    l += __shfl_xor(l, 1); l += __shfl_xor(l, 2); l += __shfl_xor(l, 4); l += __shfl_xor(l, 8);
    float inv = 1.0f / l;
    int ig = i0 + lg * 4 + rr;
    size_t base = ((size_t)b * NPAD + ig) * DD + w * 32;
    updb[base + la] = f2b(o0[rr] * inv);
    updb[base + 16 + la] = f2b(o1[rr] * inv);
  }
}

// ---------------- residual + LayerNorm; LAST=1 writes final output ----------------
template <int LAST>
__global__ __launch_bounds__(256) void k_ln(float* xf, u16* xb, const u16* y16,
                                            const float* resv, int ridx,
                                            const float* g_, const float* b_, float* outp) {
  int row = blockIdx.x * 4 + (threadIdx.x >> 6);
  int lane = threadIdx.x & 63;
  float res = resv[ridx];
  const u16* yr = y16 + (size_t)row * DD;
  float* xr = xf + (size_t)row * DD;
  int c = lane * 4;
  float4 xv = *(const float4*)(xr + c);
  u16x4 yv = *(const u16x4*)(yr + c);
  float v0 = xv.x + b2f(yv[0]) * res, v1 = xv.y + b2f(yv[1]) * res;
  float v2 = xv.z + b2f(yv[2]) * res, v3 = xv.w + b2f(yv[3]) * res;
  float sum = v0 + v1 + v2 + v3;
  sum += __shfl_xor(sum, 1); sum += __shfl_xor(sum, 2); sum += __shfl_xor(sum, 4);
  sum += __shfl_xor(sum, 8); sum += __shfl_xor(sum, 16); sum += __shfl_xor(sum, 32);
  float mean = sum * (1.0f / 256.0f);
  float d0 = v0 - mean, d1 = v1 - mean, d2 = v2 - mean, d3 = v3 - mean;
  float vs = d0 * d0 + d1 * d1 + d2 * d2 + d3 * d3;
  vs += __shfl_xor(vs, 1); vs += __shfl_xor(vs, 2); vs += __shfl_xor(vs, 4);
  vs += __shfl_xor(vs, 8); vs += __shfl_xor(vs, 16); vs += __shfl_xor(vs, 32);
  float rstd = rsqrtf(vs * (1.0f / 256.0f) + 1e-5f);
  float o0 = d0 * rstd * g_[c + 0] + b_[c + 0];
  float o1 = d1 * rstd * g_[c + 1] + b_[c + 1];
  float o2 = d2 * rstd * g_[c + 2] + b_[c + 2];
  float o3 = d3 * rstd * g_[c + 3] + b_[c + 3];
  if (!LAST) {
    *(float4*)(xr + c) = make_float4(o0, o1, o2, o3);
    u16x4 bv; bv[0] = f2b(o0); bv[1] = f2b(o1); bv[2] = f2b(o2); bv[3] = f2b(o3);
    *(u16x4*)(xb + (size_t)row * DD + c) = bv;
  } else {
    int bq = row >> 9, r = row & 511;
    if (r >= 1) {
      int p = r - 1;
      float4 val = (p < 448) ? make_float4(o0, o1, o2, o3) : make_float4(0.f, 0.f, 0.f, 0.f);
      *(float4*)(outp + ((size_t)bq * PP + p) * DD + c) = val;
    } else {
      *(float4*)(outp + ((size_t)bq * PP + 511) * DD + c) = make_float4(0.f, 0.f, 0.f, 0.f);
    }
  }
}

__global__ void k_diag(float* out, int v) {
  int gid = blockIdx.x * 64 + threadIdx.x;
  float4 r = make_float4(0.f, 0.f, 0.f, 0.f);
  if (gid == 28672) r.x = (float)v;
  *(float4*)(out + (size_t)gid * 4) = r;
}

extern "C" void kernel_launch(void* const* d_in, const int* in_sizes, int n_in,
                              void* d_out, int out_size, void* d_ws, size_t ws_size,
                              hipStream_t stream) {
  const float* embeds = (const float*)d_in[0];
  const float* xmin = (const float*)d_in[1];
  const float* xmax = (const float*)d_in[2];
  const float* ymin = (const float*)d_in[3];
  const float* ymax = (const float*)d_in[4];
  const float* width = (const float*)d_in[5];
  const float* height = (const float*)d_in[6];
  const float* empty_embed = (const float*)d_in[7];
  const float* pos_emb = (const float*)d_in[8];
  const float* cq_w = (const float*)d_in[9];
  const float* cq_b = (const float*)d_in[10];
  const float* ck_w = (const float*)d_in[11];
  const float* ck_b = (const float*)d_in[12];
  const float* pk_w = (const float*)d_in[13];
  const float* pk_b = (const float*)d_in[14];
  const float* pq_w = (const float*)d_in[15];
  const float* pq_b = (const float*)d_in[16];
  const float* cv_w = (const float*)d_in[17];
  const float* cv_b = (const float*)d_in[18];
  const float* out_w = (const float*)d_in[19];
  const float* out_b = (const float*)d_in[20];
  const float* res1 = (const float*)d_in[21];
  const float* res2 = (const float*)d_in[22];
  const float* ln1_g = (const float*)d_in[23];
  const float* ln1_b = (const float*)d_in[24];
  const float* ln2_g = (const float*)d_in[25];
  const float* ln2_b = (const float*)d_in[26];
  const float* ff1_w = (const float*)d_in[27];
  const float* ff1_b = (const float*)d_in[28];
  const float* ff2_w = (const float*)d_in[29];
  const float* ff2_b = (const float*)d_in[30];
  const int* page_ids = (const int*)d_in[31];

  char* ws = (char*)d_ws;
  size_t off = 0;
  auto alloc = [&](size_t bytes) -> void* {
    void* p = ws + off;
    off += (bytes + 255) & ~(size_t)255;
    return p;
  };
  float* xf = (float*)alloc((size_t)MM * DD * 4);
  u16* xb = (u16*)alloc((size_t)MM * DD * 2);
  u16* qh = (u16*)alloc((size_t)MM * DD * 2);
  u16* kh = (u16*)alloc((size_t)MM * DD * 2);
  u16* vt = (u16*)alloc((size_t)MM * DD * 2);
  u16* updb = (u16*)alloc((size_t)MM * DD * 2);
  u16* y16 = (u16*)alloc((size_t)MM * DD * 2);
  u16* h1b = (u16*)alloc((size_t)MM * 512 * 2);
  u16* tabC2 = (u16*)alloc((size_t)BB * NPAD * 64 * 16 * 2);
  u16* tabP2 = (u16*)alloc((size_t)BB * NPAD * 64 * 16 * 2);
  u16* relp = (u16*)alloc((size_t)BB * NPAD * NPAD * 2);
  u16* wT = (u16*)alloc((size_t)4 * 524288 * 2);
  u16* pkfsw = (u16*)alloc((size_t)4 * 16 * 64 * 16 * 2);
  u16* pqfsw = (u16*)alloc((size_t)4 * 16 * 64 * 16 * 2);
  float* gcx = (float*)alloc((size_t)BB * PP * 4);
  float* gcy = (float*)alloc((size_t)BB * PP * 4);
  float* gw = (float*)alloc((size_t)BB * PP * 4);
  float* gh_ = (float*)alloc((size_t)BB * PP * 4);
  (void)in_sizes; (void)n_in; (void)out_size;

  if (off > ws_size) {
    k_diag<<<dim3(8192), 64, 0, stream>>>((float*)d_out, 216);
    return;
  }

  k_prep<<<dim3(8192), 64, 0, stream>>>(embeds, xmin, xmax, ymin, ymax, width, height,
                                        empty_embed, page_ids, xf, xb, gcx, gcy, gw, gh_);
  k_rel<<<dim3(8192), 64, 0, stream>>>(gcx, gcy, gw, gh_, relp);
  k_wT<<<dim3(2048), 256, 0, stream>>>(cq_w, ck_w, cv_w, out_w, ff1_w, ff2_w, wT);
  k_posproj<<<dim3(512), 256, 0, stream>>>(pos_emb, pk_w, pk_b, pq_w, pq_b, pkfsw, pqfsw);

  for (int l = 0; l < 4; l++) {
    const u16* wl = wT + (size_t)l * 524288;
    k_gemm<0><<<dim3(128, 12), 256, 0, stream>>>(xb, wl, 256, cq_b + l * 256, ck_b + l * 256,
                                                 cv_b + l * 256, qh, kh, vt);
    k_tab<<<dim3(128, 16, 2), 256, 0, stream>>>(qh, kh, pkfsw, pqfsw, tabC2, tabP2, l);
    k_attn<<<dim3(512), 512, 0, stream>>>(qh, kh, vt, tabC2, tabP2, relp, updb);
    k_gemm<1><<<dim3(128, 4), 256, 0, stream>>>(updb, wl + 196608, 256, out_b + l * 256,
                                                nullptr, nullptr, y16, nullptr, nullptr);
    k_ln<0><<<dim3(2048), 256, 0, stream>>>(xf, xb, y16, res1, l, ln1_g + l * 256, ln1_b + l * 256,
                                            (float*)d_out);
    k_gemm<2><<<dim3(128, 8), 256, 0, stream>>>(xb, wl + 262144, 256, ff1_b + l * 512,
                                                nullptr, nullptr, h1b, nullptr, nullptr);
    k_gemm<1><<<dim3(128, 4), 256, 0, stream>>>(h1b, wl + 393216, 512, ff2_b + l * 256,
                                                nullptr, nullptr, y16, nullptr, nullptr);
    if (l < 3)
      k_ln<0><<<dim3(2048), 256, 0, stream>>>(xf, xb, y16, res2, l, ln2_g + l * 256,
                                              ln2_b + l * 256, (float*)d_out);
    else
      k_ln<1><<<dim3(2048), 256, 0, stream>>>(xf, xb, y16, res2, l, ln2_g + l * 256,
                                              ln2_b + l * 256, (float*)d_out);
  }
}

// Round 21
// 501.166 us; speedup vs baseline: 1.0794x; 1.0011x over previous
//
#include <hip/hip_runtime.h>
#include <math.h>

#define BB 16
#define PP 512
#define DD 256
#define HH 8
#define NPAD 512
#define NVAL 449
#define MM (BB*PP)   // 8192
#define NROWS (BB*HH*NPAD)  // 65536

typedef unsigned short u16;
typedef unsigned u32;
typedef __bf16 v8bf __attribute__((ext_vector_type(8)));
typedef float v4f __attribute__((ext_vector_type(4)));
typedef unsigned short u16x8 __attribute__((ext_vector_type(8)));
typedef unsigned short u16x4 __attribute__((ext_vector_type(4)));

static __device__ __forceinline__ float b2f(u16 u) {
  unsigned v = ((unsigned)u) << 16;
  return __builtin_bit_cast(float, v);
}
static __device__ __forceinline__ u16 f2b(float f) {
  unsigned x = __builtin_bit_cast(unsigned, f);
  unsigned lsb = (x >> 16) & 1u;
  x += 0x7fffu + lsb;
  return (u16)(x >> 16);
}
static __device__ __forceinline__ v8bf ldg8(const u16* p) {
  u16x8 u = *(const u16x8*)p;
  return __builtin_bit_cast(v8bf, u);
}
static __device__ __forceinline__ void gload16(const u16* g, u16* l) {
  __builtin_amdgcn_global_load_lds(
      (__attribute__((address_space(1))) void*)(g),
      (__attribute__((address_space(3))) void*)(l), 16, 0, 0);
}

// ---------------- prep: gather x rows + geometry ----------------
__global__ void k_prep(const float* embeds, const float* xmin, const float* xmax,
                       const float* ymin, const float* ymax, const float* width,
                       const float* height, const float* empty_embed, const int* page_ids,
                       float* xf, u16* xb, float* gcx, float* gcy, float* gw, float* gh_) {
  int bx = blockIdx.x;            // 8192 = b*512 + r
  int b = bx >> 9, r = bx & 511;
  int t = threadIdx.x;            // 64
  int c0 = t * 4;
  const float* src = nullptr;
  if (r == 0) src = empty_embed;
  else if (r <= 448) {
    int gi = page_ids[b * PP + (r - 1)];
    src = embeds + (size_t)gi * DD;
  }
  float4 fv = make_float4(0.f, 0.f, 0.f, 0.f);
  if (src) fv = *(const float4*)(src + c0);
  size_t row = (size_t)b * NPAD + r;
  *(float4*)(xf + row * DD + c0) = fv;
  u16x4 bv; bv[0] = f2b(fv.x); bv[1] = f2b(fv.y); bv[2] = f2b(fv.z); bv[3] = f2b(fv.w);
  *(u16x4*)(xb + row * DD + c0) = bv;
  if (t == 0) {
    int p = r;
    int gi = page_ids[b * PP + p];
    float cx = 0.f, cy = 0.f, ww = 1.f, hh = 1.f;
    if (gi >= 0) {
      cx = 0.5f * (xmin[gi] + xmax[gi]);
      cy = 0.5f * (ymin[gi] + ymax[gi]);
      ww = fmaxf(width[gi], 1e-3f);
      hh = fmaxf(height[gi], 1e-3f);
    }
    gcx[b * PP + p] = cx; gcy[b * PP + p] = cy;
    gw[b * PP + p] = ww;  gh_[b * PP + p] = hh;
  }
}

// ---------------- rel indices (once): relp[b][i][j] = zx | zy<<8 ----------------
__global__ __launch_bounds__(64) void k_rel(const float* gcx, const float* gcy,
                                            const float* gw, const float* gh_, u16* relp) {
  int bx = blockIdx.x;            // 8192 = b*512 + i
  int b = bx >> 9, i = bx & 511;
  int t = threadIdx.x;
  float cxi = 0.f, cyi = 0.f, wi = 1.f, hi = 1.f;
  if (i > 0) {
    cxi = gcx[b * PP + i - 1]; cyi = gcy[b * PP + i - 1];
    wi = gw[b * PP + i - 1];   hi = gh_[b * PP + i - 1];
  }
  u16* dst = relp + ((size_t)b * NPAD + i) * NPAD;
#pragma unroll
  for (int jj = 0; jj < 8; jj++) {
    int j = jj * 64 + t;
    u16 pk = (u16)(32 | (32 << 8));
    if (j > 0) {
      float cxj = gcx[b * PP + j - 1], cyj = gcy[b * PP + j - 1];
      float dxf = rintf((cxj - cxi) / wi);
      float dyf = rintf((cyj - cyi) / hi);
      int zx = (int)(fminf(fmaxf(dxf, -32.f), 31.f)) + 32;
      int zy = (int)(fminf(fmaxf(dyf, -32.f), 31.f)) + 32;
      pk = (u16)(zx | (zy << 8));
    }
    dst[j] = pk;
  }
}

// ---------------- weight transposes (once) ----------------
__global__ __launch_bounds__(256) void k_wT(const float* cq, const float* ck, const float* cv,
                                            const float* ow, const float* f1, const float* f2,
                                            u16* wT) {
  __shared__ u16 lds[32][33];
  int bx = blockIdx.x;           // 2048
  int l = bx >> 9, r = bx & 511;
  const float* src; int N, k0, n0; u16* dst; int dstStride;
  if (r < 192) {
    int mat = r / 64, rr = r % 64;
    k0 = (rr >> 3) * 32; n0 = (rr & 7) * 32;
    src = (mat == 0 ? cq : mat == 1 ? ck : cv) + (size_t)l * 65536;
    N = 256; dst = wT + (size_t)l * 524288 + mat * 65536; dstStride = 256;
  } else if (r < 256) {
    int rr = r - 192;
    k0 = (rr >> 3) * 32; n0 = (rr & 7) * 32;
    src = ow + (size_t)l * 65536; N = 256;
    dst = wT + (size_t)l * 524288 + 196608; dstStride = 256;
  } else if (r < 384) {
    int rr = r - 256;
    k0 = (rr >> 4) * 32; n0 = (rr & 15) * 32;
    src = f1 + (size_t)l * 131072; N = 512;
    dst = wT + (size_t)l * 524288 + 262144; dstStride = 256;
  } else {
    int rr = r - 384;
    k0 = (rr >> 3) * 32; n0 = (rr & 7) * 32;
    src = f2 + (size_t)l * 131072; N = 256;
    dst = wT + (size_t)l * 524288 + 393216; dstStride = 512;
  }
  int tx = threadIdx.x & 31, ty = threadIdx.x >> 5;
#pragma unroll
  for (int yy = 0; yy < 4; yy++) {
    int y = ty + yy * 8;
    lds[y][tx] = f2b(src[(size_t)(k0 + y) * N + n0 + tx]);
  }
  __syncthreads();
#pragma unroll
  for (int yy = 0; yy < 4; yy++) {
    int y = ty + yy * 8;
    dst[(size_t)(n0 + y) * dstStride + k0 + tx] = lds[tx][y];
  }
}

// ---------------- position projections: [L][16 ch][64 z][16 d] bf16, ch=c*8+h ----------------
__global__ __launch_bounds__(256) void k_posproj(const float* pe, const float* pkw, const float* pkb,
                                                 const float* pqw, const float* pqb,
                                                 u16* pkfsw, u16* pqfsw) {
  int gid = blockIdx.x * 256 + threadIdx.x;   // 131072
  int d = gid & 15, z = (gid >> 4) & 63, ch = (gid >> 10) & 15, l = (gid >> 14) & 3, tab = gid >> 16;
  const float* W = (tab ? pqw : pkw) + (size_t)l * 65536;
  const float* Bb = (tab ? pqb : pkb) + (size_t)l * 256;
  int col = (ch >> 3) * 128 + (ch & 7) * 16 + d;
  float s = Bb[col];
  const float* per = pe + (size_t)z * 256;
  for (int kk = 0; kk < 256; kk++) s += per[kk] * W[(size_t)kk * 256 + col];
  u16* dst = tab ? pqfsw : pkfsw;
  dst[(((size_t)l * 16 + ch) * 64 + z) * 16 + d] = f2b(s);
}

// ---------------- MFMA GEMM, BM=64 x BN, BK=64, 4 waves 2x2, LDS dbuf, T2 swizzle ----------------
template <int EPI, int BN>
__global__ __launch_bounds__(256) void k_gemm(const u16* A, const u16* W, int K,
                                              const float* bias0, const float* bias1, const float* bias2,
                                              void* out0, void* out1, void* out2) {
  constexpr int FJ = BN / 32;          // b-frags per wave (2 or 4)
  constexpr int BCH = BN / 32;         // B stage iterations
  __shared__ u16 As[2][4096];          // [64][64]
  __shared__ u16 Bs[2][BN * 64];
  int w = threadIdx.x >> 6, lane = threadIdx.x & 63;
  int la = lane & 15, lg = lane >> 4;
  int wm = w & 1, wn = w >> 1;
  int m0 = blockIdx.x * 64;
  int n0 = blockIdx.y * BN;
  v4f acc[2][FJ] = {};
  int nt = K >> 6;
#define STAGE(kb, buf) do {                                                      \
    _Pragma("unroll")                                                            \
    for (int p_ = 0; p_ < 2; p_++) {                                             \
      int e_ = threadIdx.x + p_ * 256;                                           \
      int row_ = e_ >> 3, ch_ = e_ & 7;                                          \
      int sk_ = (ch_ ^ (row_ & 7)) * 8;                                          \
      gload16(A + (size_t)(m0 + row_) * K + (kb) + sk_, &As[buf][e_ * 8]);       \
    }                                                                            \
    _Pragma("unroll")                                                            \
    for (int p_ = 0; p_ < BCH; p_++) {                                           \
      int e_ = threadIdx.x + p_ * 256;                                           \
      int row_ = e_ >> 3, ch_ = e_ & 7;                                          \
      int sk_ = (ch_ ^ (row_ & 7)) * 8;                                          \
      gload16(W + (size_t)(n0 + row_) * K + (kb) + sk_, &Bs[buf][e_ * 8]);       \
    }                                                                            \
  } while (0)
  STAGE(0, 0);
  __syncthreads();
  for (int t = 0; t < nt; t++) {
    int cur = t & 1;
    if (t + 1 < nt) STAGE((t + 1) << 6, cur ^ 1);
    const u16* as = As[cur];
    const u16* bs = Bs[cur];
#pragma unroll
    for (int ks = 0; ks < 2; ks++) {
      int ra0 = wm * 32 + la, ra1 = wm * 32 + 16 + la;
      v8bf a0 = ldg8(as + ra0 * 64 + ((ks * 32 + lg * 8) ^ ((ra0 & 7) << 3)));
      v8bf a1 = ldg8(as + ra1 * 64 + ((ks * 32 + lg * 8) ^ ((ra1 & 7) << 3)));
      v8bf bf[FJ];
#pragma unroll
      for (int fj = 0; fj < FJ; fj++) {
        int rb = wn * (BN / 2) + fj * 16 + la;
        bf[fj] = ldg8(bs + rb * 64 + ((ks * 32 + lg * 8) ^ ((rb & 7) << 3)));
      }
#pragma unroll
      for (int fj = 0; fj < FJ; fj++) {
        acc[0][fj] = __builtin_amdgcn_mfma_f32_16x16x32_bf16(a0, bf[fj], acc[0][fj], 0, 0, 0);
        acc[1][fj] = __builtin_amdgcn_mfma_f32_16x16x32_bf16(a1, bf[fj], acc[1][fj], 0, 0, 0);
      }
    }
    __syncthreads();
  }
#undef STAGE
#pragma unroll
  for (int fi = 0; fi < 2; fi++)
#pragma unroll
    for (int fj = 0; fj < FJ; fj++)
#pragma unroll
      for (int rr = 0; rr < 4; rr++) {
        int m = m0 + wm * 32 + fi * 16 + lg * 4 + rr;
        int n = n0 + wn * (BN / 2) + fj * 16 + la;
        float v = acc[fi][fj][rr];
        if (EPI == 0) {
          const float* bp = (n < 256 ? bias0 : n < 512 ? bias1 : bias2);
          v += bp[n & 255];
          int b = m >> 9, i = m & 511, h = (n & 255) >> 5, d = n & 31;
          if (n < 512) {
            u16* dst = (u16*)(n < 256 ? out0 : out1);
            dst[(((size_t)(b * 8 + h)) * NPAD + i) * 32 + d] = f2b(v);
          } else {
            ((u16*)out2)[(((size_t)(b * 8 + h)) * 32 + d) * NPAD + i] = f2b(v);
          }
        } else if (EPI == 1) {
          ((u16*)out0)[(size_t)m * 256 + n] = f2b(v + bias0[n]);
        } else {
          float x = v + bias0[n];
          float g = 0.5f * x * (1.0f + erff(x * 0.70710678118654752f));
          ((u16*)out0)[(size_t)m * 512 + n] = f2b(g);
        }
      }
}

// ---------------- pos tables (merged, vector stores): z=0 -> tabC2; z=1 -> tabP2 ----------------
__global__ __launch_bounds__(256) void k_tab(const u16* qh, const u16* kh,
                                             const u16* pkfsw, const u16* pqfsw,
                                             u16* tabC2, u16* tabP2, int l) {
  __shared__ __align__(16) u16 qs[4][8][32];
  const u16* srcp = blockIdx.z ? kh : qh;
  const u16* tbl = blockIdx.z ? pqfsw : pkfsw;
  u16* dst = blockIdx.z ? tabP2 : tabC2;
  int b = blockIdx.y, i0 = blockIdx.x * 4;
  int t = threadIdx.x;
  {
    int flat = t * 4;
    int si = flat >> 8, sh = (flat >> 5) & 7, sd = flat & 31;
    *(u16x4*)&qs[si][sh][sd] =
        *(const u16x4*)(srcp + (((size_t)(b * 8 + sh)) * NPAD + i0 + si) * 32 + sd);
  }
  __syncthreads();
  int z = t & 63, cg = t >> 6;
  u16x8 W0[4], W1[4];
#pragma unroll
  for (int cc = 0; cc < 4; cc++) {
    int ch = cg * 4 + cc;
    const u16* pp = tbl + (((size_t)l * 16 + ch) * 64 + z) * 16;
    W0[cc] = *(const u16x8*)pp;
    W1[cc] = *(const u16x8*)(pp + 8);
  }
#pragma unroll
  for (int ii = 0; ii < 4; ii++) {
    u16x4 res;
#pragma unroll
    for (int cc = 0; cc < 4; cc++) {
      int ch = cg * 4 + cc, c = ch >> 3, h = ch & 7;
      const u16* qq = &qs[ii][h][c * 16];
      float s = 0.f;
#pragma unroll
      for (int d = 0; d < 8; d++) s += b2f(qq[d]) * b2f(W0[cc][d]);
#pragma unroll
      for (int d = 0; d < 8; d++) s += b2f(qq[d + 8]) * b2f(W1[cc][d]);
      res[cc] = f2b(s);
    }
    *(u16x4*)&dst[(((size_t)b * NPAD + i0 + ii) * 64 + z) * 16 + cg * 4] = res;
  }
}

// ---------------- fused MFMA attention: un-split, 7 tiles + j=448 tail, direct updb ----------------
// grid 512 (XCD-swizzled): b(4b) x i-tile(5b). 8 waves = 8 heads.
__global__ __launch_bounds__(512) void k_attn(const u16* qh, const u16* kh, const u16* vtp,
                                              const u16* tabC2, const u16* tabP2, const u16* relp,
                                              u16* updb) {
  __shared__ u32 posb[4][16][68];            // packed bf16 h-pairs
  __shared__ __align__(16) u16 ps[8][16][72];
  int bid = blockIdx.x;
  int idx = (bid & 7) * 64 + (bid >> 3);     // 8 XCD chunks of 64 -> 2 b each
  int b = idx >> 5;
  int i0 = (idx & 31) * 16;
  int t = threadIdx.x, w = t >> 6, lane = t & 63;
  int la = lane & 15, lg = lane >> 4;
  v8bf qa = ldg8(qh + (((size_t)(b * 8 + w)) * NPAD + i0 + la) * 32 + lg * 8);
  float lrow[4] = {0.f, 0.f, 0.f, 0.f};
  v4f o0 = {}; v4f o1 = {};
  const float scale = 0.17677669529663687f;
  const float MC = 8.0f;
  const u16* kbase = kh + ((size_t)(b * 8 + w)) * NPAD * 32;
  const u16* vbase = vtp + ((size_t)(b * 8 + w)) * 32 * NPAD;
  const u16* rbase = relp + ((size_t)b * NPAD + i0) * NPAD;
  u16x8 Av[2], Bv[2], Cv[2], Dv[2];
  bool fval[2];
#define FETCH(J0) do {                                                          \
    _Pragma("unroll")                                                           \
    for (int pp = 0; pp < 2; pp++) {                                            \
      int p_ = t + pp * 512;                                                    \
      int si_ = p_ >> 6, sj_ = p_ & 63;                                         \
      int ig_ = i0 + si_, jg_ = (J0) + sj_;                                     \
      bool v_ = (ig_ > 0 && jg_ > 0);                                           \
      fval[pp] = v_;                                                            \
      if (v_) {                                                                 \
        unsigned rp_ = rbase[(size_t)si_ * NPAD + jg_];                         \
        int zx_ = rp_ & 255, zy_ = rp_ >> 8;                                    \
        Av[pp] = *(const u16x8*)(tabC2 + (((size_t)b * NPAD + ig_) * 64 + zx_) * 16);     \
        Cv[pp] = *(const u16x8*)(tabP2 + (((size_t)b * NPAD + jg_) * 64 + zx_) * 16);     \
        Bv[pp] = *(const u16x8*)(tabC2 + (((size_t)b * NPAD + ig_) * 64 + zy_) * 16 + 8); \
        Dv[pp] = *(const u16x8*)(tabP2 + (((size_t)b * NPAD + jg_) * 64 + zy_) * 16 + 8); \
      }                                                                         \
    }                                                                           \
  } while (0)
  FETCH(0);
  for (int tt = 0; tt < 7; tt++) {
    int j0 = tt * 64;
#pragma unroll
    for (int pp = 0; pp < 2; pp++) {
      int p = t + pp * 512;
      int si = p >> 6, sj = p & 63;
      float pos[8] = {0.f, 0.f, 0.f, 0.f, 0.f, 0.f, 0.f, 0.f};
      if (fval[pp]) {
#pragma unroll
        for (int h = 0; h < 8; h++)
          pos[h] = (b2f(Av[pp][h]) + b2f(Cv[pp][h])) + (b2f(Bv[pp][h]) + b2f(Dv[pp][h]));
      }
#pragma unroll
      for (int hp = 0; hp < 4; hp++)
        posb[hp][si][sj] = (u32)f2b(pos[2 * hp]) | ((u32)f2b(pos[2 * hp + 1]) << 16);
    }
    __syncthreads();
    v4f s[4];
#pragma unroll
    for (int fj = 0; fj < 4; fj++) {
      v8bf kf = ldg8(kbase + (size_t)(j0 + fj * 16 + la) * 32 + lg * 8);
      v4f zero = {};
      s[fj] = __builtin_amdgcn_mfma_f32_16x16x32_bf16(qa, kf, zero, 0, 0, 0);
    }
    float pvv[4][4];
    int wsel = (w & 1) ? 16 : 0;
#pragma unroll
    for (int fj = 0; fj < 4; fj++) {
#pragma unroll
      for (int rr = 0; rr < 4; rr++) {
        int il = lg * 4 + rr;
        u32 pk = posb[w >> 1][il][fj * 16 + la];
        float posv = b2f((u16)(pk >> wsel));
        float lv = (s[fj][rr] + posv) * scale;
        pvv[fj][rr] = __expf(lv - MC);
      }
    }
    __syncthreads();
    if (tt + 1 < 7) FETCH(j0 + 64);
#pragma unroll
    for (int rr = 0; rr < 4; rr++)
      lrow[rr] += pvv[0][rr] + pvv[1][rr] + pvv[2][rr] + pvv[3][rr];
#pragma unroll
    for (int fj = 0; fj < 4; fj++)
#pragma unroll
      for (int rr = 0; rr < 4; rr++)
        ps[w][lg * 4 + rr][fj * 16 + la] = f2b(pvv[fj][rr]);
    v8bf pa0 = __builtin_bit_cast(v8bf, *(const u16x8*)&ps[w][la][lg * 8]);
    v8bf pa1 = __builtin_bit_cast(v8bf, *(const u16x8*)&ps[w][la][32 + lg * 8]);
    v8bf v00 = ldg8(vbase + (size_t)la * NPAD + j0 + lg * 8);
    v8bf v01 = ldg8(vbase + (size_t)la * NPAD + j0 + 32 + lg * 8);
    v8bf v10 = ldg8(vbase + (size_t)(16 + la) * NPAD + j0 + lg * 8);
    v8bf v11 = ldg8(vbase + (size_t)(16 + la) * NPAD + j0 + 32 + lg * 8);
    o0 = __builtin_amdgcn_mfma_f32_16x16x32_bf16(pa0, v00, o0, 0, 0, 0);
    o0 = __builtin_amdgcn_mfma_f32_16x16x32_bf16(pa1, v01, o0, 0, 0, 0);
    o1 = __builtin_amdgcn_mfma_f32_16x16x32_bf16(pa0, v10, o1, 0, 0, 0);
    o1 = __builtin_amdgcn_mfma_f32_16x16x32_bf16(pa1, v11, o1, 0, 0, 0);
  }
#undef FETCH
  {
    v8bf kf = ldg8(kbase + (size_t)448 * 32 + lg * 8);
    float dot = 0.f;
#pragma unroll
    for (int e = 0; e < 8; e++) dot += (float)qa[e] * (float)kf[e];
    dot += __shfl_xor(dot, 16);
    dot += __shfl_xor(dot, 32);
    int ig = i0 + la;
    float pos = 0.f;
    if (ig > 0) {
      unsigned rp = relp[((size_t)b * NPAD + ig) * NPAD + 448];
      int zx = rp & 255, zy = rp >> 8;
      pos = b2f(tabC2[(((size_t)b * NPAD + ig) * 64 + zx) * 16 + w])
          + b2f(tabP2[(((size_t)b * NPAD + 448) * 64 + zx) * 16 + w])
          + b2f(tabC2[(((size_t)b * NPAD + ig) * 64 + zy) * 16 + 8 + w])
          + b2f(tabP2[(((size_t)b * NPAD + 448) * 64 + zy) * 16 + 8 + w]);
    }
    float p448 = __expf((dot + pos) * scale - MC);
    float va = b2f(vbase[(size_t)la * NPAD + 448]);
    float vb_ = b2f(vbase[(size_t)(16 + la) * NPAD + 448]);
#pragma unroll
    for (int rr = 0; rr < 4; rr++) {
      float pr = __shfl(p448, lg * 4 + rr);
      o0[rr] += pr * va;
      o1[rr] += pr * vb_;
      if (la == 0) lrow[rr] += pr;
    }
  }
#pragma unroll
  for (int rr = 0; rr < 4; rr++) {
    float l = lrow[rr];
    l += __shfl_xor(l, 1); l += __shfl_xor(l, 2); l += __shfl_xor(l, 4); l += __shfl_xor(l, 8);
    float inv = 1.0f / l;
    int ig = i0 + lg * 4 + rr;
    size_t base = ((size_t)b * NPAD + ig) * DD + w * 32;
    updb[base + la] = f2b(o0[rr] * inv);
    updb[base + 16 + la] = f2b(o1[rr] * inv);
  }
}

// ---------------- residual + LayerNorm; LAST=1 writes final output ----------------
template <int LAST>
__global__ __launch_bounds__(256) void k_ln(float* xf, u16* xb, const u16* y16,
                                            const float* resv, int ridx,
                                            const float* g_, const float* b_, float* outp) {
  int row = blockIdx.x * 4 + (threadIdx.x >> 6);
  int lane = threadIdx.x & 63;
  float res = resv[ridx];
  const u16* yr = y16 + (size_t)row * DD;
  float* xr = xf + (size_t)row * DD;
  int c = lane * 4;
  float4 xv = *(const float4*)(xr + c);
  u16x4 yv = *(const u16x4*)(yr + c);
  float v0 = xv.x + b2f(yv[0]) * res, v1 = xv.y + b2f(yv[1]) * res;
  float v2 = xv.z + b2f(yv[2]) * res, v3 = xv.w + b2f(yv[3]) * res;
  float sum = v0 + v1 + v2 + v3;
  sum += __shfl_xor(sum, 1); sum += __shfl_xor(sum, 2); sum += __shfl_xor(sum, 4);
  sum += __shfl_xor(sum, 8); sum += __shfl_xor(sum, 16); sum += __shfl_xor(sum, 32);
  float mean = sum * (1.0f / 256.0f);
  float d0 = v0 - mean, d1 = v1 - mean, d2 = v2 - mean, d3 = v3 - mean;
  float vs = d0 * d0 + d1 * d1 + d2 * d2 + d3 * d3;
  vs += __shfl_xor(vs, 1); vs += __shfl_xor(vs, 2); vs += __shfl_xor(vs, 4);
  vs += __shfl_xor(vs, 8); vs += __shfl_xor(vs, 16); vs += __shfl_xor(vs, 32);
  float rstd = rsqrtf(vs * (1.0f / 256.0f) + 1e-5f);
  float o0 = d0 * rstd * g_[c + 0] + b_[c + 0];
  float o1 = d1 * rstd * g_[c + 1] + b_[c + 1];
  float o2 = d2 * rstd * g_[c + 2] + b_[c + 2];
  float o3 = d3 * rstd * g_[c + 3] + b_[c + 3];
  if (!LAST) {
    *(float4*)(xr + c) = make_float4(o0, o1, o2, o3);
    u16x4 bv; bv[0] = f2b(o0); bv[1] = f2b(o1); bv[2] = f2b(o2); bv[3] = f2b(o3);
    *(u16x4*)(xb + (size_t)row * DD + c) = bv;
  } else {
    int bq = row >> 9, r = row & 511;
    if (r >= 1) {
      int p = r - 1;
      float4 val = (p < 448) ? make_float4(o0, o1, o2, o3) : make_float4(0.f, 0.f, 0.f, 0.f);
      *(float4*)(outp + ((size_t)bq * PP + p) * DD + c) = val;
    } else {
      *(float4*)(outp + ((size_t)bq * PP + 511) * DD + c) = make_float4(0.f, 0.f, 0.f, 0.f);
    }
  }
}

__global__ void k_diag(float* out, int v) {
  int gid = blockIdx.x * 64 + threadIdx.x;
  float4 r = make_float4(0.f, 0.f, 0.f, 0.f);
  if (gid == 28672) r.x = (float)v;
  *(float4*)(out + (size_t)gid * 4) = r;
}

extern "C" void kernel_launch(void* const* d_in, const int* in_sizes, int n_in,
                              void* d_out, int out_size, void* d_ws, size_t ws_size,
                              hipStream_t stream) {
  const float* embeds = (const float*)d_in[0];
  const float* xmin = (const float*)d_in[1];
  const float* xmax = (const float*)d_in[2];
  const float* ymin = (const float*)d_in[3];
  const float* ymax = (const float*)d_in[4];
  const float* width = (const float*)d_in[5];
  const float* height = (const float*)d_in[6];
  const float* empty_embed = (const float*)d_in[7];
  const float* pos_emb = (const float*)d_in[8];
  const float* cq_w = (const float*)d_in[9];
  const float* cq_b = (const float*)d_in[10];
  const float* ck_w = (const float*)d_in[11];
  const float* ck_b = (const float*)d_in[12];
  const float* pk_w = (const float*)d_in[13];
  const float* pk_b = (const float*)d_in[14];
  const float* pq_w = (const float*)d_in[15];
  const float* pq_b = (const float*)d_in[16];
  const float* cv_w = (const float*)d_in[17];
  const float* cv_b = (const float*)d_in[18];
  const float* out_w = (const float*)d_in[19];
  const float* out_b = (const float*)d_in[20];
  const float* res1 = (const float*)d_in[21];
  const float* res2 = (const float*)d_in[22];
  const float* ln1_g = (const float*)d_in[23];
  const float* ln1_b = (const float*)d_in[24];
  const float* ln2_g = (const float*)d_in[25];
  const float* ln2_b = (const float*)d_in[26];
  const float* ff1_w = (const float*)d_in[27];
  const float* ff1_b = (const float*)d_in[28];
  const float* ff2_w = (const float*)d_in[29];
  const float* ff2_b = (const float*)d_in[30];
  const int* page_ids = (const int*)d_in[31];

  char* ws = (char*)d_ws;
  size_t off = 0;
  auto alloc = [&](size_t bytes) -> void* {
    void* p = ws + off;
    off += (bytes + 255) & ~(size_t)255;
    return p;
  };
  float* xf = (float*)alloc((size_t)MM * DD * 4);
  u16* xb = (u16*)alloc((size_t)MM * DD * 2);
  u16* qh = (u16*)alloc((size_t)MM * DD * 2);
  u16* kh = (u16*)alloc((size_t)MM * DD * 2);
  u16* vt = (u16*)alloc((size_t)MM * DD * 2);
  u16* updb = (u16*)alloc((size_t)MM * DD * 2);
  u16* y16 = (u16*)alloc((size_t)MM * DD * 2);
  u16* h1b = (u16*)alloc((size_t)MM * 512 * 2);
  u16* tabC2 = (u16*)alloc((size_t)BB * NPAD * 64 * 16 * 2);
  u16* tabP2 = (u16*)alloc((size_t)BB * NPAD * 64 * 16 * 2);
  u16* relp = (u16*)alloc((size_t)BB * NPAD * NPAD * 2);
  u16* wT = (u16*)alloc((size_t)4 * 524288 * 2);
  u16* pkfsw = (u16*)alloc((size_t)4 * 16 * 64 * 16 * 2);
  u16* pqfsw = (u16*)alloc((size_t)4 * 16 * 64 * 16 * 2);
  float* gcx = (float*)alloc((size_t)BB * PP * 4);
  float* gcy = (float*)alloc((size_t)BB * PP * 4);
  float* gw = (float*)alloc((size_t)BB * PP * 4);
  float* gh_ = (float*)alloc((size_t)BB * PP * 4);
  (void)in_sizes; (void)n_in; (void)out_size;

  if (off > ws_size) {
    k_diag<<<dim3(8192), 64, 0, stream>>>((float*)d_out, 216);
    return;
  }

  k_prep<<<dim3(8192), 64, 0, stream>>>(embeds, xmin, xmax, ymin, ymax, width, height,
                                        empty_embed, page_ids, xf, xb, gcx, gcy, gw, gh_);
  k_rel<<<dim3(8192), 64, 0, stream>>>(gcx, gcy, gw, gh_, relp);
  k_wT<<<dim3(2048), 256, 0, stream>>>(cq_w, ck_w, cv_w, out_w, ff1_w, ff2_w, wT);
  k_posproj<<<dim3(512), 256, 0, stream>>>(pos_emb, pk_w, pk_b, pq_w, pq_b, pkfsw, pqfsw);

  for (int l = 0; l < 4; l++) {
    const u16* wl = wT + (size_t)l * 524288;
    k_gemm<0, 128><<<dim3(128, 6), 256, 0, stream>>>(xb, wl, 256, cq_b + l * 256, ck_b + l * 256,
                                                     cv_b + l * 256, qh, kh, vt);
    k_tab<<<dim3(128, 16, 2), 256, 0, stream>>>(qh, kh, pkfsw, pqfsw, tabC2, tabP2, l);
    k_attn<<<dim3(512), 512, 0, stream>>>(qh, kh, vt, tabC2, tabP2, relp, updb);
    k_gemm<1, 64><<<dim3(128, 4), 256, 0, stream>>>(updb, wl + 196608, 256, out_b + l * 256,
                                                    nullptr, nullptr, y16, nullptr, nullptr);
    k_ln<0><<<dim3(2048), 256, 0, stream>>>(xf, xb, y16, res1, l, ln1_g + l * 256, ln1_b + l * 256,
                                            (float*)d_out);
    k_gemm<2, 128><<<dim3(128, 4), 256, 0, stream>>>(xb, wl + 262144, 256, ff1_b + l * 512,
                                                     nullptr, nullptr, h1b, nullptr, nullptr);
    k_gemm<1, 64><<<dim3(128, 4), 256, 0, stream>>>(h1b, wl + 393216, 512, ff2_b + l * 256,
                                                    nullptr, nullptr, y16, nullptr, nullptr);
    if (l < 3)
      k_ln<0><<<dim3(2048), 256, 0, stream>>>(xf, xb, y16, res2, l, ln2_g + l * 256,
                                              ln2_b + l * 256, (float*)d_out);
    else
      k_ln<1><<<dim3(2048), 256, 0, stream>>>(xf, xb, y16, res2, l, ln2_g + l * 256,
                                              ln2_b + l * 256, (float*)d_out);
  }
}